// Round 2
// baseline (282.448 us; speedup 1.0000x reference)
//
#include <hip/hip_runtime.h>

#define NV 4096
#define NMASK 4095
#define NN 7
#define KK1 49
#define KK2 169
#define C0 16
#define C1 32
#define C2 32
#define F1LEN 1568          // C1*KK1
#define RSTR 888            // u32 words per vertex in f1T: 49*18=882 used, pad to 888 (mult of 4)
#define QSTR 18             // u32 words per q (16 used = 32 bf16, 2 pad)
#define AGLEN 5408          // C1*KK2 flat agg2 per vertex
#define MTILES 43264        // (NV*KK2)/16

typedef unsigned int uint;
typedef unsigned short ushort;
typedef __attribute__((ext_vector_type(8))) short short8v;
typedef __attribute__((ext_vector_type(4))) float float4v;

static __device__ __forceinline__ ushort f2bf(float f) {
    union { float f; uint u; } v; v.f = f;
    uint r = (v.u + 0x7fffu + ((v.u >> 16) & 1u)) >> 16;
    return (ushort)r;
}
static __device__ __forceinline__ float bflo(uint w) { return __uint_as_float(w << 16); }
static __device__ __forceinline__ float bfhi(uint w) { return __uint_as_float(w & 0xffff0000u); }

// ================= K1: labels -> f1T (bf16, transposed layout [v][q*18 + c/2]) =================
#define VB1 16
#define NT1 256
__global__ __launch_bounds__(256) void k1_kernel(
    const float* __restrict__ labels, const int* __restrict__ nbrs,
    const float* __restrict__ mask1, const float* __restrict__ adj1,
    const float* __restrict__ W1, const float* __restrict__ b1,
    const float* __restrict__ al1, uint* __restrict__ f1T)
{
    __shared__ __align__(16) float Ls[22][16];
    __shared__ float mms[VB1 * 7 * 49];
    __shared__ int rowOf[VB1][7];
    __shared__ __align__(16) float W1s[32][16];
    __shared__ float b1s[32];
    __shared__ float al1s;
    __shared__ __align__(16) uint uni[VB1 * RSTR];   // aggs (fp32, 784/vtx) then yT (bf16 packed)

    int t = threadIdx.x;
    int v0 = blockIdx.x * VB1;

    for (int e = t; e < 22 * 16; e += NT1) {
        int r = e >> 4, c = e & 15;
        int vv = (v0 - 3 + r + NV) & NMASK;
        Ls[r][c] = labels[vv * 16 + c];
    }
    for (int e = t; e < VB1 * 7; e += NT1) {
        int vl = e / 7, u = e % 7;
        int nb = nbrs[(v0 + vl) * 7 + u];
        rowOf[vl][u] = (nb - v0 + 3 + NV) & NMASK;
    }
    for (int e = t; e < 512; e += NT1) W1s[e >> 4][e & 15] = W1[e];
    if (t < 32) b1s[t] = b1[t];
    if (t == 0) al1s = al1[0];
    for (int e = t; e < VB1 * 343; e += NT1) {
        int vl = e / 343, r = e % 343, u = r / 49, ij = r % 49;
        int i = ij / 7, j = ij % 7;
        const float* mb = mask1 + (size_t)(v0 + vl) * 49 + u * 7;
        mms[e] = mb[i] * mb[j];
    }
    __syncthreads();

    float* aggs = (float*)uni;   // [vl][c*49+ij], stride 784
    // ---- agg phase: item = (vl, ij) ----
    for (int it = 0; it < 4; ++it) {
        int w = t + NT1 * it;
        if (w < VB1 * 49) {
            int vl = w / 49, ij = w % 49;
            float4 a0 = {0,0,0,0}, a1 = a0, a2 = a0, a3 = a0;
            #pragma unroll
            for (int u = 0; u < 7; ++u) {
                float mm = mms[(vl * 7 + u) * 49 + ij];
                int r = rowOf[vl][u];
                const float4* lr = (const float4*)&Ls[r][0];
                float4 l0 = lr[0], l1 = lr[1], l2 = lr[2], l3 = lr[3];
                a0.x += mm*l0.x; a0.y += mm*l0.y; a0.z += mm*l0.z; a0.w += mm*l0.w;
                a1.x += mm*l1.x; a1.y += mm*l1.y; a1.z += mm*l1.z; a1.w += mm*l1.w;
                a2.x += mm*l2.x; a2.y += mm*l2.y; a2.z += mm*l2.z; a2.w += mm*l2.w;
                a3.x += mm*l3.x; a3.y += mm*l3.y; a3.z += mm*l3.z; a3.w += mm*l3.w;
            }
            float av = al1s * adj1[(size_t)(v0 + vl) * 49 + ij];
            float ac[16] = {a0.x,a0.y,a0.z,a0.w, a1.x,a1.y,a1.z,a1.w,
                            a2.x,a2.y,a2.z,a2.w, a3.x,a3.y,a3.z,a3.w};
            #pragma unroll
            for (int c = 0; c < 16; ++c)
                aggs[vl * 784 + c * 49 + ij] = ac[c] + av;
        }
    }
    __syncthreads();

    // ---- matmul: item = (vl, p); x rows preloaded, W1 row shared across 4 items ----
    float4 x4[4][4];
    #pragma unroll
    for (int it = 0; it < 4; ++it) {
        int w = t + NT1 * it;
        int off = (w < 784) ? ((w / 49) * 784 + (w % 49) * 16) : 0;
        const float4* xp = (const float4*)(aggs + off);
        x4[it][0] = xp[0]; x4[it][1] = xp[1]; x4[it][2] = xp[2]; x4[it][3] = xp[3];
    }
    uint yp[4][16];
    #pragma unroll
    for (int co = 0; co < 32; ++co) {
        const float4* wr = (const float4*)&W1s[co][0];
        float4 w0 = wr[0], w1 = wr[1], w2 = wr[2], w3 = wr[3];
        float bb = b1s[co];
        #pragma unroll
        for (int it = 0; it < 4; ++it) {
            float s = bb;
            s += x4[it][0].x*w0.x + x4[it][0].y*w0.y + x4[it][0].z*w0.z + x4[it][0].w*w0.w;
            s += x4[it][1].x*w1.x + x4[it][1].y*w1.y + x4[it][1].z*w1.z + x4[it][1].w*w1.w;
            s += x4[it][2].x*w2.x + x4[it][2].y*w2.y + x4[it][2].z*w2.z + x4[it][2].w*w2.w;
            s += x4[it][3].x*w3.x + x4[it][3].y*w3.y + x4[it][3].z*w3.z + x4[it][3].w*w3.w;
            s = fmaxf(s, 0.f);
            ushort h = f2bf(s);
            if (co & 1) yp[it][co >> 1] |= ((uint)h << 16);
            else        yp[it][co >> 1] = (uint)h;
        }
    }
    __syncthreads();   // all aggs reads done -> reuse uni as yT

    ushort* yts = (ushort*)uni;
    #pragma unroll
    for (int it = 0; it < 4; ++it) {
        int w = t + NT1 * it;
        if (w < 784) {
            int vl = w / 49, p = w % 49;
            #pragma unroll
            for (int wq = 0; wq < 16; ++wq) {
                uint pk = yp[it][wq];
                int f0 = p * 32 + 2 * wq;
                int c0 = f0 / 49, q0 = f0 % 49;
                int f1v = f0 + 1;
                int c1 = f1v / 49, q1 = f1v % 49;
                yts[(vl * RSTR + q0 * QSTR + (c0 >> 1)) * 2 + (c0 & 1)] = (ushort)(pk & 0xffffu);
                yts[(vl * RSTR + q1 * QSTR + (c1 >> 1)) * 2 + (c1 & 1)] = (ushort)(pk >> 16);
            }
        }
    }
    __syncthreads();
    for (int e = t; e < VB1 * RSTR; e += NT1)
        f1T[(size_t)v0 * RSTR + e] = uni[e];
}

// ================= K2: gather -> aggB (bf16, flat [v][c*169+ij]) =================
#define VB2 16
#define NT2 512
__global__ __launch_bounds__(512) void k2_kernel(
    const uint* __restrict__ f1T, const int* __restrict__ nbrs,
    const int* __restrict__ idx2, const float* __restrict__ mask2,
    const float* __restrict__ adj2, const float* __restrict__ al2,
    ushort* __restrict__ aggB)
{
    __shared__ __align__(16) uint fs[22 * RSTR];
    __shared__ int rowOf[VB2][7];
    __shared__ float al2s;
    int t = threadIdx.x;
    int v0 = blockIdx.x * VB2;

    for (int e = t; e < VB2 * 7; e += NT2) {
        int vl = e / 7, u = e % 7;
        int nb = nbrs[(v0 + vl) * 7 + u];
        rowOf[vl][u] = (nb - v0 + 3 + NV) & NMASK;
    }
    if (t == 0) al2s = al2[0];
    for (int e4 = t; e4 < 22 * (RSTR / 4); e4 += NT2) {
        int r = e4 / (RSTR / 4), w4 = e4 % (RSTR / 4);
        int vv = (v0 - 3 + r + NV) & NMASK;
        ((uint4*)fs)[r * (RSTR / 4) + w4] = ((const uint4*)(f1T + (size_t)vv * RSTR))[w4];
    }
    __syncthreads();

    for (int it = 0; it < 6; ++it) {
        int w = t + NT2 * it;
        if (w < VB2 * KK2) {
            int vl = w / KK2, ij = w % KK2;
            int i = ij / 13, j = ij % 13;
            int v = v0 + vl;
            float acc[32];
            #pragma unroll
            for (int c = 0; c < 32; ++c) acc[c] = 0.f;
            const float* mb = mask2 + (size_t)v * 91;
            const int*   ib = idx2 + (size_t)v * 91;
            #pragma unroll
            for (int u = 0; u < 7; ++u) {
                float mm = mb[u * 13 + i] * mb[u * 13 + j];
                int q = ib[u * 13 + i] * 7 + ib[u * 13 + j];
                const uint2* p2 = (const uint2*)(fs + rowOf[vl][u] * RSTR + q * QSTR);
                #pragma unroll
                for (int e = 0; e < 8; ++e) {
                    uint2 d = p2[e];
                    acc[4*e+0] += mm * bflo(d.x);
                    acc[4*e+1] += mm * bfhi(d.x);
                    acc[4*e+2] += mm * bflo(d.y);
                    acc[4*e+3] += mm * bfhi(d.y);
                }
            }
            float av = al2s * adj2[(size_t)v * KK2 + ij];
            ushort* outp = aggB + (size_t)v * AGLEN + ij;
            #pragma unroll
            for (int c = 0; c < 32; ++c) outp[c * KK2] = f2bf(acc[c] + av);
        }
    }
}

// ================= K3: streaming MFMA GEMM (M=692224, K=32, N=32) + relu + g_repr fold =========
__global__ __launch_bounds__(256) void k3_kernel(
    const ushort* __restrict__ aggB, const float* __restrict__ W2,
    const float* __restrict__ b2, float* __restrict__ gr)
{
    __shared__ float grs[32];
    int t = threadIdx.x;
    if (t < 32) grs[t] = 0.f;
    __syncthreads();

    int lane = t & 63;
    int r16 = lane & 15, kg = lane >> 4;
    // B fragment: B[k][n] = W2[n][k]; slot (lane,e) <-> k = kg*8+e (same mapping as A => exact)
    short8v bf0, bf1;
    #pragma unroll
    for (int e = 0; e < 8; ++e) {
        bf0[e] = (short)f2bf(W2[r16 * 32 + kg * 8 + e]);
        bf1[e] = (short)f2bf(W2[(r16 + 16) * 32 + kg * 8 + e]);
    }
    float bias0 = b2[r16], bias1 = b2[r16 + 16];

    int wave = blockIdx.x * 4 + (t >> 6);
    for (int tile = wave; tile < MTILES; tile += 5408) {
        int mbase = tile * 16;
        const uint4* ap = (const uint4*)(aggB + (size_t)mbase * 32);
        uint4 araw = ap[r16 * 4 + kg];      // row mbase+r16, k-slots kg*8..kg*8+7
        short8v a = *reinterpret_cast<short8v*>(&araw);
        float4v z = {0.f, 0.f, 0.f, 0.f};
        float4v d0 = __builtin_amdgcn_mfma_f32_16x16x32_bf16(a, bf0, z, 0, 0, 0);
        float4v d1 = __builtin_amdgcn_mfma_f32_16x16x32_bf16(a, bf1, z, 0, 0, 0);
        #pragma unroll
        for (int r = 0; r < 4; ++r) {
            int m = mbase + kg * 4 + r;
            int p = m % KK2;
            float y0 = fmaxf(d0[r] + bias0, 0.f);
            float y1 = fmaxf(d1[r] + bias1, 0.f);
            int n0 = p * 32 + r16;
            atomicAdd(&grs[n0 / KK2], y0);
            atomicAdd(&grs[(n0 + 16) / KK2], y1);
        }
    }
    __syncthreads();
    if (t < 32) atomicAdd(&gr[t], grs[t]);
}

// ================= final FC =================
__global__ __launch_bounds__(64) void fc_kernel(
    const float* __restrict__ gr, const float* __restrict__ Wfc,
    const float* __restrict__ bfc, float* __restrict__ out)
{
    int t = threadIdx.x;
    float g = (t < C2) ? gr[t] : 0.f;
    if (t < C2) out[1 + t] = g;
    float p = (t < C2) ? g * Wfc[t] : 0.f;
    #pragma unroll
    for (int off = 32; off > 0; off >>= 1) p += __shfl_down(p, off);
    if (t == 0) out[0] = p + bfc[0];
}

// ================= fallback path (round-1, needs only 25.7 MB ws) =================
__global__ __launch_bounds__(64) void lvl1_kernel(
    const float* __restrict__ labels, const int* __restrict__ nbrs,
    const float* __restrict__ mask1, const float* __restrict__ adj1,
    const float* __restrict__ W1, const float* __restrict__ b1,
    const float* __restrict__ al1, float* __restrict__ f1out)
{
    __shared__ float Ls[NN][C0];
    __shared__ float m1s[NN][7];
    __shared__ float a1s[KK1];
    __shared__ float aggsh[C0 * KK1];
    __shared__ float W1s[C1 * 17];
    __shared__ float b1s[C1];
    int v = blockIdx.x, t = threadIdx.x;
    for (int e = t; e < NN * C0; e += 64) {
        int u = e >> 4, c = e & 15;
        Ls[u][c] = labels[(size_t)nbrs[v * NN + u] * C0 + c];
    }
    for (int e = t; e < KK1; e += 64) {
        m1s[e / 7][e % 7] = mask1[(size_t)v * KK1 + e];
        a1s[e] = adj1[(size_t)v * KK1 + e];
    }
    for (int e = t; e < C1 * C0; e += 64) W1s[(e >> 4) * 17 + (e & 15)] = W1[e];
    if (t < C1) b1s[t] = b1[t];
    float alpha = al1[0];
    __syncthreads();
    for (int e = t; e < C0 * KK1; e += 64) {
        int c = e / KK1, ij = e % KK1, i = ij / 7, j = ij % 7;
        float s = 0.f;
        #pragma unroll
        for (int u = 0; u < NN; ++u) s += Ls[u][c] * (m1s[u][i] * m1s[u][j]);
        aggsh[e] = s + alpha * a1s[ij];
    }
    __syncthreads();
    int co = t & 31;
    for (int e = t; e < F1LEN; e += 64) {
        int p = e >> 5;
        float s = b1s[co];
        #pragma unroll
        for (int c = 0; c < C0; ++c) s += aggsh[p * C0 + c] * W1s[co * 17 + c];
        f1out[(size_t)v * F1LEN + e] = fmaxf(s, 0.f);
    }
}

#define F1PAD 56
#define AGPAD 177
__global__ __launch_bounds__(192) void lvl2_kernel(
    const float* __restrict__ f1, const int* __restrict__ nbrs,
    const int* __restrict__ idx2, const float* __restrict__ mask2,
    const float* __restrict__ adj2, const float* __restrict__ W2,
    const float* __restrict__ b2, const float* __restrict__ al2,
    float* __restrict__ gr)
{
    __shared__ float f1s[C1 * F1PAD];
    __shared__ float aggT[C1 * AGPAD];
    __shared__ float W2s[C2 * C1];
    __shared__ float b2s[C2];
    __shared__ float grs[C2];
    __shared__ int nbs[NN];
    int v = blockIdx.x, t = threadIdx.x;
    if (t < NN) nbs[t] = nbrs[v * NN + t];
    if (t < C2) { b2s[t] = b2[t]; grs[t] = 0.f; }
    for (int e = t; e < C2 * C1; e += 192) W2s[e] = W2[e];
    float alpha = al2[0];
    bool act = (t < KK2);
    float mmr[NN]; int qr[NN];
    float acc[C1];
    if (act) {
        int i = t / 13, j = t % 13;
        const float* mbase = mask2 + (size_t)v * NN * 13;
        const int* ibase = idx2 + (size_t)v * NN * 13;
        #pragma unroll
        for (int u = 0; u < NN; ++u) {
            mmr[u] = mbase[u * 13 + i] * mbase[u * 13 + j];
            qr[u] = ibase[u * 13 + i] * 7 + ibase[u * 13 + j];
        }
    }
    #pragma unroll
    for (int c = 0; c < C1; ++c) acc[c] = 0.f;
    int dst[9]; int nd = 0;
    for (int e = t; e < F1LEN; e += 192) dst[nd++] = (e / 49) * F1PAD + (e % 49);
    for (int u = 0; u < NN; ++u) {
        __syncthreads();
        const float* src = f1 + (size_t)nbs[u] * F1LEN;
        { int k = 0; for (int e = t; e < F1LEN; e += 192) f1s[dst[k++]] = src[e]; }
        __syncthreads();
        if (act) {
            float mv = mmr[u]; int q = qr[u];
            #pragma unroll
            for (int c = 0; c < C1; ++c) acc[c] += mv * f1s[c * F1PAD + q];
        }
    }
    if (act) {
        float a2v = alpha * adj2[(size_t)v * KK2 + t];
        #pragma unroll
        for (int c = 0; c < C1; ++c) {
            int f = c * KK2 + t;
            aggT[(f & 31) * AGPAD + (f >> 5)] = acc[c] + a2v;
        }
    }
    __syncthreads();
    if (act) {
        int p = t;
        float ar[C1];
        #pragma unroll
        for (int c2 = 0; c2 < C1; ++c2) ar[c2] = aggT[c2 * AGPAD + p];
        int chA = (p * 32) / KK2;
        int csplit = KK2 - (p * 32 - chA * KK2);
        float sA = 0.f, sB = 0.f;
        #pragma unroll
        for (int co = 0; co < C2; ++co) {
            float s = b2s[co];
            #pragma unroll
            for (int k = 0; k < 8; ++k) {
                float4 wv = *(const float4*)(&W2s[co * C1 + 4 * k]);
                s += ar[4*k+0]*wv.x + ar[4*k+1]*wv.y + ar[4*k+2]*wv.z + ar[4*k+3]*wv.w;
            }
            s = fmaxf(s, 0.f);
            if (co < csplit) sA += s; else sB += s;
        }
        atomicAdd(&grs[chA], sA);
        if (csplit < 32) atomicAdd(&grs[chA + 1], sB);
    }
    __syncthreads();
    if (t < C2) atomicAdd(&gr[t], grs[t]);
}

extern "C" void kernel_launch(void* const* d_in, const int* in_sizes, int n_in,
                              void* d_out, int out_size, void* d_ws, size_t ws_size,
                              hipStream_t stream)
{
    const float* labels = (const float*)d_in[0];
    const int*   nbrs   = (const int*)d_in[1];
    /* d_in[2] = idx1: all zeros, unused */
    const float* mask1  = (const float*)d_in[3];
    const int*   idx2   = (const int*)d_in[4];
    const float* mask2  = (const float*)d_in[5];
    const float* adj1   = (const float*)d_in[6];
    const float* adj2   = (const float*)d_in[7];
    const float* W1     = (const float*)d_in[8];
    const float* b1     = (const float*)d_in[9];
    const float* W2     = (const float*)d_in[10];
    const float* b2     = (const float*)d_in[11];
    const float* al1    = (const float*)d_in[12];
    const float* al2    = (const float*)d_in[13];
    const float* Wfc    = (const float*)d_in[14];
    const float* bfc    = (const float*)d_in[15];

    const size_t f1T_bytes = (size_t)NV * RSTR * sizeof(uint);      // 14,548,992
    const size_t aggB_bytes = (size_t)NV * AGLEN * sizeof(ushort);  // 44,302,336
    const size_t need = f1T_bytes + aggB_bytes + 128;

    if (ws_size >= need) {
        uint*   f1T  = (uint*)d_ws;
        ushort* aggB = (ushort*)((char*)d_ws + f1T_bytes);
        float*  gr   = (float*)((char*)d_ws + f1T_bytes + aggB_bytes);
        hipMemsetAsync(gr, 0, C2 * sizeof(float), stream);
        k1_kernel<<<NV / VB1, NT1, 0, stream>>>(labels, nbrs, mask1, adj1, W1, b1, al1, f1T);
        k2_kernel<<<NV / VB2, NT2, 0, stream>>>(f1T, nbrs, idx2, mask2, adj2, al2, aggB);
        k3_kernel<<<1352, 256, 0, stream>>>(aggB, W2, b2, gr);
        fc_kernel<<<1, 64, 0, stream>>>(gr, Wfc, bfc, (float*)d_out);
    } else {
        float* f1 = (float*)d_ws;
        float* gr = (float*)((char*)d_ws + (size_t)NV * F1LEN * sizeof(float));
        hipMemsetAsync(gr, 0, C2 * sizeof(float), stream);
        lvl1_kernel<<<NV, 64, 0, stream>>>(labels, nbrs, mask1, adj1, W1, b1, al1, f1);
        lvl2_kernel<<<NV, 192, 0, stream>>>(f1, nbrs, idx2, mask2, adj2, W2, b2, al2, gr);
        fc_kernel<<<1, 64, 0, stream>>>(gr, Wfc, bfc, (float*)d_out);
    }
}

// Round 3
// 143.279 us; speedup vs baseline: 1.9713x; 1.9713x over previous
//
#include <hip/hip_runtime.h>

#define NV 4096
#define NMASK 4095
#define NN 7
#define KK1 49
#define KK2 169
#define C0 16
#define C1 32
#define C2 32
#define F1LEN 1568          // C1*KK1
#define RSTR 888            // u32 words per vertex in f1T: 49*18=882 used, pad to 888 (mult of 4)
#define QSTR 18             // u32 words per q (16 used = 32 bf16, 2 pad)
#define AGLEN 5408          // C1*KK2 flat agg2 per vertex
#define PT 11               // p-tiles of 16 rows covering KK2=169
#define GV 186              // vertex groups; active waves = 11*186 = 2046
#define NB3 512             // k3 blocks (2048 waves)

typedef unsigned int uint;
typedef unsigned short ushort;
typedef __attribute__((ext_vector_type(8))) short short8v;
typedef __attribute__((ext_vector_type(4))) float float4v;

static __device__ __forceinline__ ushort f2bf(float f) {
    union { float f; uint u; } v; v.f = f;
    uint r = (v.u + 0x7fffu + ((v.u >> 16) & 1u)) >> 16;
    return (ushort)r;
}
static __device__ __forceinline__ float bflo(uint w) { return __uint_as_float(w << 16); }
static __device__ __forceinline__ float bfhi(uint w) { return __uint_as_float(w & 0xffff0000u); }

// ================= K1: labels -> f1T (bf16, transposed layout [v][q*18 + c/2]) =================
#define VB1 16
#define NT1 256
__global__ __launch_bounds__(256) void k1_kernel(
    const float* __restrict__ labels, const int* __restrict__ nbrs,
    const float* __restrict__ mask1, const float* __restrict__ adj1,
    const float* __restrict__ W1, const float* __restrict__ b1,
    const float* __restrict__ al1, uint* __restrict__ f1T)
{
    __shared__ __align__(16) float Ls[22][16];
    __shared__ float mms[VB1 * 7 * 49];
    __shared__ int rowOf[VB1][7];
    __shared__ __align__(16) float W1s[32][16];
    __shared__ float b1s[32];
    __shared__ float al1s;
    __shared__ __align__(16) uint uni[VB1 * RSTR];   // aggs (fp32, 784/vtx) then yT (bf16 packed)

    int t = threadIdx.x;
    int v0 = blockIdx.x * VB1;

    for (int e = t; e < 22 * 16; e += NT1) {
        int r = e >> 4, c = e & 15;
        int vv = (v0 - 3 + r + NV) & NMASK;
        Ls[r][c] = labels[vv * 16 + c];
    }
    for (int e = t; e < VB1 * 7; e += NT1) {
        int vl = e / 7, u = e % 7;
        int nb = nbrs[(v0 + vl) * 7 + u];
        rowOf[vl][u] = (nb - v0 + 3 + NV) & NMASK;
    }
    for (int e = t; e < 512; e += NT1) W1s[e >> 4][e & 15] = W1[e];
    if (t < 32) b1s[t] = b1[t];
    if (t == 0) al1s = al1[0];
    for (int e = t; e < VB1 * 343; e += NT1) {
        int vl = e / 343, r = e % 343, u = r / 49, ij = r % 49;
        int i = ij / 7, j = ij % 7;
        const float* mb = mask1 + (size_t)(v0 + vl) * 49 + u * 7;
        mms[e] = mb[i] * mb[j];
    }
    __syncthreads();

    float* aggs = (float*)uni;   // [vl][c*49+ij], stride 784
    for (int it = 0; it < 4; ++it) {
        int w = t + NT1 * it;
        if (w < VB1 * 49) {
            int vl = w / 49, ij = w % 49;
            float4 a0 = {0,0,0,0}, a1 = a0, a2 = a0, a3 = a0;
            #pragma unroll
            for (int u = 0; u < 7; ++u) {
                float mm = mms[(vl * 7 + u) * 49 + ij];
                int r = rowOf[vl][u];
                const float4* lr = (const float4*)&Ls[r][0];
                float4 l0 = lr[0], l1 = lr[1], l2 = lr[2], l3 = lr[3];
                a0.x += mm*l0.x; a0.y += mm*l0.y; a0.z += mm*l0.z; a0.w += mm*l0.w;
                a1.x += mm*l1.x; a1.y += mm*l1.y; a1.z += mm*l1.z; a1.w += mm*l1.w;
                a2.x += mm*l2.x; a2.y += mm*l2.y; a2.z += mm*l2.z; a2.w += mm*l2.w;
                a3.x += mm*l3.x; a3.y += mm*l3.y; a3.z += mm*l3.z; a3.w += mm*l3.w;
            }
            float av = al1s * adj1[(size_t)(v0 + vl) * 49 + ij];
            float ac[16] = {a0.x,a0.y,a0.z,a0.w, a1.x,a1.y,a1.z,a1.w,
                            a2.x,a2.y,a2.z,a2.w, a3.x,a3.y,a3.z,a3.w};
            #pragma unroll
            for (int c = 0; c < 16; ++c)
                aggs[vl * 784 + c * 49 + ij] = ac[c] + av;
        }
    }
    __syncthreads();

    float4 x4[4][4];
    #pragma unroll
    for (int it = 0; it < 4; ++it) {
        int w = t + NT1 * it;
        int off = (w < 784) ? ((w / 49) * 784 + (w % 49) * 16) : 0;
        const float4* xp = (const float4*)(aggs + off);
        x4[it][0] = xp[0]; x4[it][1] = xp[1]; x4[it][2] = xp[2]; x4[it][3] = xp[3];
    }
    uint yp[4][16];
    #pragma unroll
    for (int co = 0; co < 32; ++co) {
        const float4* wr = (const float4*)&W1s[co][0];
        float4 w0 = wr[0], w1 = wr[1], w2 = wr[2], w3 = wr[3];
        float bb = b1s[co];
        #pragma unroll
        for (int it = 0; it < 4; ++it) {
            float s = bb;
            s += x4[it][0].x*w0.x + x4[it][0].y*w0.y + x4[it][0].z*w0.z + x4[it][0].w*w0.w;
            s += x4[it][1].x*w1.x + x4[it][1].y*w1.y + x4[it][1].z*w1.z + x4[it][1].w*w1.w;
            s += x4[it][2].x*w2.x + x4[it][2].y*w2.y + x4[it][2].z*w2.z + x4[it][2].w*w2.w;
            s += x4[it][3].x*w3.x + x4[it][3].y*w3.y + x4[it][3].z*w3.z + x4[it][3].w*w3.w;
            s = fmaxf(s, 0.f);
            ushort h = f2bf(s);
            if (co & 1) yp[it][co >> 1] |= ((uint)h << 16);
            else        yp[it][co >> 1] = (uint)h;
        }
    }
    __syncthreads();

    ushort* yts = (ushort*)uni;
    #pragma unroll
    for (int it = 0; it < 4; ++it) {
        int w = t + NT1 * it;
        if (w < 784) {
            int vl = w / 49, p = w % 49;
            #pragma unroll
            for (int wq = 0; wq < 16; ++wq) {
                uint pk = yp[it][wq];
                int f0 = p * 32 + 2 * wq;
                int c0 = f0 / 49, q0 = f0 % 49;
                int f1v = f0 + 1;
                int c1 = f1v / 49, q1 = f1v % 49;
                yts[(vl * RSTR + q0 * QSTR + (c0 >> 1)) * 2 + (c0 & 1)] = (ushort)(pk & 0xffffu);
                yts[(vl * RSTR + q1 * QSTR + (c1 >> 1)) * 2 + (c1 & 1)] = (ushort)(pk >> 16);
            }
        }
    }
    __syncthreads();
    for (int e = t; e < VB1 * RSTR; e += NT1)
        f1T[(size_t)v0 * RSTR + e] = uni[e];
}

// ================= K2: gather -> aggB (bf16, flat [v][c*169+ij]) =================
#define VB2 16
#define NT2 512
__global__ __launch_bounds__(512) void k2_kernel(
    const uint* __restrict__ f1T, const int* __restrict__ nbrs,
    const int* __restrict__ idx2, const float* __restrict__ mask2,
    const float* __restrict__ adj2, const float* __restrict__ al2,
    ushort* __restrict__ aggB)
{
    __shared__ __align__(16) uint fs[22 * RSTR];
    __shared__ int rowOf[VB2][7];
    __shared__ float al2s;
    int t = threadIdx.x;
    int v0 = blockIdx.x * VB2;

    for (int e = t; e < VB2 * 7; e += NT2) {
        int vl = e / 7, u = e % 7;
        int nb = nbrs[(v0 + vl) * 7 + u];
        rowOf[vl][u] = (nb - v0 + 3 + NV) & NMASK;
    }
    if (t == 0) al2s = al2[0];
    for (int e4 = t; e4 < 22 * (RSTR / 4); e4 += NT2) {
        int r = e4 / (RSTR / 4), w4 = e4 % (RSTR / 4);
        int vv = (v0 - 3 + r + NV) & NMASK;
        ((uint4*)fs)[r * (RSTR / 4) + w4] = ((const uint4*)(f1T + (size_t)vv * RSTR))[w4];
    }
    __syncthreads();

    for (int it = 0; it < 6; ++it) {
        int w = t + NT2 * it;
        if (w < VB2 * KK2) {
            int vl = w / KK2, ij = w % KK2;
            int i = ij / 13, j = ij % 13;
            int v = v0 + vl;
            float acc[32];
            #pragma unroll
            for (int c = 0; c < 32; ++c) acc[c] = 0.f;
            const float* mb = mask2 + (size_t)v * 91;
            const int*   ib = idx2 + (size_t)v * 91;
            #pragma unroll
            for (int u = 0; u < 7; ++u) {
                float mm = mb[u * 13 + i] * mb[u * 13 + j];
                int q = ib[u * 13 + i] * 7 + ib[u * 13 + j];
                const uint2* p2 = (const uint2*)(fs + rowOf[vl][u] * RSTR + q * QSTR);
                #pragma unroll
                for (int e = 0; e < 8; ++e) {
                    uint2 d = p2[e];
                    acc[4*e+0] += mm * bflo(d.x);
                    acc[4*e+1] += mm * bfhi(d.x);
                    acc[4*e+2] += mm * bflo(d.y);
                    acc[4*e+3] += mm * bfhi(d.y);
                }
            }
            float av = al2s * adj2[(size_t)v * KK2 + ij];
            ushort* outp = aggB + (size_t)v * AGLEN + ij;
            #pragma unroll
            for (int c = 0; c < 32; ++c) outp[c * KK2] = f2bf(acc[c] + av);
        }
    }
}

// ===== K3: p-tile-partitioned streaming MFMA GEMM; register fold, one atomic pass at end =====
__global__ __launch_bounds__(256) void k3_kernel(
    const ushort* __restrict__ aggB, const float* __restrict__ W2,
    const float* __restrict__ b2, float* __restrict__ gpart)
{
    __shared__ float grs[32];
    int t = threadIdx.x;
    if (t < 32) grs[t] = 0.f;
    __syncthreads();

    int lane = t & 63;
    int r16 = lane & 15, kg = lane >> 4;
    // B fragments: B[k][n] = W2[n][k]; k-slot mapping identical on A and B => exact
    short8v bf0, bf1;
    #pragma unroll
    for (int e = 0; e < 8; ++e) {
        bf0[e] = (short)f2bf(W2[r16 * 32 + kg * 8 + e]);
        bf1[e] = (short)f2bf(W2[(r16 + 16) * 32 + kg * 8 + e]);
    }
    float bias0 = b2[r16], bias1 = b2[r16 + 16];

    int w  = blockIdx.x * 4 + (t >> 6);
    int pt = w % PT;            // fixed p-tile for this wave
    int g  = w / PT;            // vertex group
    int p0 = pt * 16;
    int prow = p0 + r16; if (prow > KK2 - 1) prow = KK2 - 1;   // clamp tail in-bounds

    float s0[4] = {0.f,0.f,0.f,0.f}, s1[4] = {0.f,0.f,0.f,0.f};
    if (g < GV) {
        for (int v = g; v < NV; v += GV) {
            const uint4* ap = (const uint4*)(aggB + (size_t)v * AGLEN);
            uint4 araw = ap[prow * 4 + kg];          // 1KB/wave contiguous
            short8v a = *reinterpret_cast<short8v*>(&araw);
            float4v z = {0.f, 0.f, 0.f, 0.f};
            float4v d0 = __builtin_amdgcn_mfma_f32_16x16x32_bf16(a, bf0, z, 0, 0, 0);
            float4v d1 = __builtin_amdgcn_mfma_f32_16x16x32_bf16(a, bf1, z, 0, 0, 0);
            #pragma unroll
            for (int r = 0; r < 4; ++r) {
                s0[r] += fmaxf(d0[r] + bias0, 0.f);
                s1[r] += fmaxf(d1[r] + bias1, 0.f);
            }
        }
        #pragma unroll
        for (int r = 0; r < 4; ++r) {
            int p = p0 + kg * 4 + r;
            if (p < KK2) {                            // channel is loop-invariant per slot
                int f0 = p * 32 + r16;
                atomicAdd(&grs[f0 / KK2], s0[r]);
                atomicAdd(&grs[(f0 + 16) / KK2], s1[r]);
            }
        }
    }
    __syncthreads();
    if (t < 32) gpart[blockIdx.x * 32 + t] = grs[t];   // plain store, no global atomics
}

// ================= final: reduce gpart + FC =================
__global__ __launch_bounds__(256) void fc_kernel(
    const float* __restrict__ gpart, const float* __restrict__ Wfc,
    const float* __restrict__ bfc, float* __restrict__ out)
{
    __shared__ float red[8][32];
    int t = threadIdx.x;
    int ch = t & 31, seg = t >> 5;
    float s = 0.f;
    for (int b = seg; b < NB3; b += 8) s += gpart[b * 32 + ch];
    red[seg][ch] = s;
    __syncthreads();
    if (t < 32) {
        float g = 0.f;
        #pragma unroll
        for (int k = 0; k < 8; ++k) g += red[k][t];
        out[1 + t] = g;
        red[0][t] = g * Wfc[t];
    }
    __syncthreads();
    if (t == 0) {
        float p = bfc[0];
        #pragma unroll
        for (int k = 0; k < 32; ++k) p += red[0][k];
        out[0] = p;
    }
}

// ================= fallback path (round-1, needs only 25.7 MB ws) =================
__global__ __launch_bounds__(64) void lvl1_kernel(
    const float* __restrict__ labels, const int* __restrict__ nbrs,
    const float* __restrict__ mask1, const float* __restrict__ adj1,
    const float* __restrict__ W1, const float* __restrict__ b1,
    const float* __restrict__ al1, float* __restrict__ f1out)
{
    __shared__ float Ls[NN][C0];
    __shared__ float m1s[NN][7];
    __shared__ float a1s[KK1];
    __shared__ float aggsh[C0 * KK1];
    __shared__ float W1s[C1 * 17];
    __shared__ float b1s[C1];
    int v = blockIdx.x, t = threadIdx.x;
    for (int e = t; e < NN * C0; e += 64) {
        int u = e >> 4, c = e & 15;
        Ls[u][c] = labels[(size_t)nbrs[v * NN + u] * C0 + c];
    }
    for (int e = t; e < KK1; e += 64) {
        m1s[e / 7][e % 7] = mask1[(size_t)v * KK1 + e];
        a1s[e] = adj1[(size_t)v * KK1 + e];
    }
    for (int e = t; e < C1 * C0; e += 64) W1s[(e >> 4) * 17 + (e & 15)] = W1[e];
    if (t < C1) b1s[t] = b1[t];
    float alpha = al1[0];
    __syncthreads();
    for (int e = t; e < C0 * KK1; e += 64) {
        int c = e / KK1, ij = e % KK1, i = ij / 7, j = ij % 7;
        float s = 0.f;
        #pragma unroll
        for (int u = 0; u < NN; ++u) s += Ls[u][c] * (m1s[u][i] * m1s[u][j]);
        aggsh[e] = s + alpha * a1s[ij];
    }
    __syncthreads();
    int co = t & 31;
    for (int e = t; e < F1LEN; e += 64) {
        int p = e >> 5;
        float s = b1s[co];
        #pragma unroll
        for (int c = 0; c < C0; ++c) s += aggsh[p * C0 + c] * W1s[co * 17 + c];
        f1out[(size_t)v * F1LEN + e] = fmaxf(s, 0.f);
    }
}

#define F1PAD 56
#define AGPAD 177
__global__ __launch_bounds__(192) void lvl2_kernel(
    const float* __restrict__ f1, const int* __restrict__ nbrs,
    const int* __restrict__ idx2, const float* __restrict__ mask2,
    const float* __restrict__ adj2, const float* __restrict__ W2,
    const float* __restrict__ b2, const float* __restrict__ al2,
    float* __restrict__ gr)
{
    __shared__ float f1s[C1 * F1PAD];
    __shared__ float aggT[C1 * AGPAD];
    __shared__ float W2s[C2 * C1];
    __shared__ float b2s[C2];
    __shared__ float grs[C2];
    __shared__ int nbs[NN];
    int v = blockIdx.x, t = threadIdx.x;
    if (t < NN) nbs[t] = nbrs[v * NN + t];
    if (t < C2) { b2s[t] = b2[t]; grs[t] = 0.f; }
    for (int e = t; e < C2 * C1; e += 192) W2s[e] = W2[e];
    float alpha = al2[0];
    bool act = (t < KK2);
    float mmr[NN]; int qr[NN];
    float acc[C1];
    if (act) {
        int i = t / 13, j = t % 13;
        const float* mbase = mask2 + (size_t)v * NN * 13;
        const int* ibase = idx2 + (size_t)v * NN * 13;
        #pragma unroll
        for (int u = 0; u < NN; ++u) {
            mmr[u] = mbase[u * 13 + i] * mbase[u * 13 + j];
            qr[u] = ibase[u * 13 + i] * 7 + ibase[u * 13 + j];
        }
    }
    #pragma unroll
    for (int c = 0; c < C1; ++c) acc[c] = 0.f;
    int dst[9]; int nd = 0;
    for (int e = t; e < F1LEN; e += 192) dst[nd++] = (e / 49) * F1PAD + (e % 49);
    for (int u = 0; u < NN; ++u) {
        __syncthreads();
        const float* src = f1 + (size_t)nbs[u] * F1LEN;
        { int k = 0; for (int e = t; e < F1LEN; e += 192) f1s[dst[k++]] = src[e]; }
        __syncthreads();
        if (act) {
            float mv = mmr[u]; int q = qr[u];
            #pragma unroll
            for (int c = 0; c < C1; ++c) acc[c] += mv * f1s[c * F1PAD + q];
        }
    }
    if (act) {
        float a2v = alpha * adj2[(size_t)v * KK2 + t];
        #pragma unroll
        for (int c = 0; c < C1; ++c) {
            int f = c * KK2 + t;
            aggT[(f & 31) * AGPAD + (f >> 5)] = acc[c] + a2v;
        }
    }
    __syncthreads();
    if (act) {
        int p = t;
        float ar[C1];
        #pragma unroll
        for (int c2 = 0; c2 < C1; ++c2) ar[c2] = aggT[c2 * AGPAD + p];
        int chA = (p * 32) / KK2;
        int csplit = KK2 - (p * 32 - chA * KK2);
        float sA = 0.f, sB = 0.f;
        #pragma unroll
        for (int co = 0; co < C2; ++co) {
            float s = b2s[co];
            #pragma unroll
            for (int k = 0; k < 8; ++k) {
                float4 wv = *(const float4*)(&W2s[co * C1 + 4 * k]);
                s += ar[4*k+0]*wv.x + ar[4*k+1]*wv.y + ar[4*k+2]*wv.z + ar[4*k+3]*wv.w;
            }
            s = fmaxf(s, 0.f);
            if (co < csplit) sA += s; else sB += s;
        }
        atomicAdd(&grs[chA], sA);
        if (csplit < 32) atomicAdd(&grs[chA + 1], sB);
    }
    __syncthreads();
    if (t < C2) atomicAdd(&gr[t], grs[t]);
}

__global__ __launch_bounds__(64) void fc_small_kernel(
    const float* __restrict__ gr, const float* __restrict__ Wfc,
    const float* __restrict__ bfc, float* __restrict__ out)
{
    int t = threadIdx.x;
    float g = (t < C2) ? gr[t] : 0.f;
    if (t < C2) out[1 + t] = g;
    float p = (t < C2) ? g * Wfc[t] : 0.f;
    #pragma unroll
    for (int off = 32; off > 0; off >>= 1) p += __shfl_down(p, off);
    if (t == 0) out[0] = p + bfc[0];
}

extern "C" void kernel_launch(void* const* d_in, const int* in_sizes, int n_in,
                              void* d_out, int out_size, void* d_ws, size_t ws_size,
                              hipStream_t stream)
{
    const float* labels = (const float*)d_in[0];
    const int*   nbrs   = (const int*)d_in[1];
    /* d_in[2] = idx1: all zeros, unused */
    const float* mask1  = (const float*)d_in[3];
    const int*   idx2   = (const int*)d_in[4];
    const float* mask2  = (const float*)d_in[5];
    const float* adj1   = (const float*)d_in[6];
    const float* adj2   = (const float*)d_in[7];
    const float* W1     = (const float*)d_in[8];
    const float* b1     = (const float*)d_in[9];
    const float* W2     = (const float*)d_in[10];
    const float* b2     = (const float*)d_in[11];
    const float* al1    = (const float*)d_in[12];
    const float* al2    = (const float*)d_in[13];
    const float* Wfc    = (const float*)d_in[14];
    const float* bfc    = (const float*)d_in[15];

    const size_t f1T_bytes = (size_t)NV * RSTR * sizeof(uint);      // 14,548,992
    const size_t aggB_bytes = (size_t)NV * AGLEN * sizeof(ushort);  // 44,302,336
    const size_t need = f1T_bytes + aggB_bytes + 128;

    if (ws_size >= need) {
        uint*   f1T   = (uint*)d_ws;
        ushort* aggB  = (ushort*)((char*)d_ws + f1T_bytes);
        float*  gpart = (float*)d_ws;    // aliases f1T region (dead once k3 runs); 64KB
        k1_kernel<<<NV / VB1, NT1, 0, stream>>>(labels, nbrs, mask1, adj1, W1, b1, al1, f1T);
        k2_kernel<<<NV / VB2, NT2, 0, stream>>>(f1T, nbrs, idx2, mask2, adj2, al2, aggB);
        k3_kernel<<<NB3, 256, 0, stream>>>(aggB, W2, b2, gpart);
        fc_kernel<<<1, 256, 0, stream>>>(gpart, Wfc, bfc, (float*)d_out);
    } else {
        float* f1 = (float*)d_ws;
        float* gr = (float*)((char*)d_ws + (size_t)NV * F1LEN * sizeof(float));
        hipMemsetAsync(gr, 0, C2 * sizeof(float), stream);
        lvl1_kernel<<<NV, 64, 0, stream>>>(labels, nbrs, mask1, adj1, W1, b1, al1, f1);
        lvl2_kernel<<<NV, 192, 0, stream>>>(f1, nbrs, idx2, mask2, adj2, W2, b2, al2, gr);
        fc_small_kernel<<<1, 64, 0, stream>>>(gr, Wfc, bfc, (float*)d_out);
    }
}

// Round 4
// 74.783 us; speedup vs baseline: 3.7769x; 1.9159x over previous
//
#include <hip/hip_runtime.h>

#define NV 4096
#define NMASK 4095
#define NN 7
#define KK1 49
#define KK2 169
#define C0 16
#define C1 32
#define C2 32
#define F1LEN 1568
#define RSTR 888            // u32 words per vertex in f1T: 49*18=882 used, pad 888
#define QSTR 18             // u32 words per q (16 used = 32 bf16, 2 pad)

typedef unsigned int uint;
typedef unsigned short ushort;
typedef __attribute__((ext_vector_type(8))) short short8v;
typedef __attribute__((ext_vector_type(4))) float float4v;

static __device__ __forceinline__ ushort f2bf(float f) {
    union { float f; uint u; } v; v.f = f;
    uint r = (v.u + 0x7fffu + ((v.u >> 16) & 1u)) >> 16;
    return (ushort)r;
}
static __device__ __forceinline__ float bflo(uint w) { return __uint_as_float(w << 16); }
static __device__ __forceinline__ float bfhi(uint w) { return __uint_as_float(w & 0xffff0000u); }

// ================= K1: labels -> f1T (bf16, layout [v][q*18 + c/2]) — low-pressure rewrite ====
#define VB1 8
#define NT1 256
__global__ __launch_bounds__(256) void k1_kernel(
    const float* __restrict__ labels, const int* __restrict__ nbrs,
    const float* __restrict__ mask1, const float* __restrict__ adj1,
    const float* __restrict__ W1, const float* __restrict__ b1,
    const float* __restrict__ al1, uint* __restrict__ f1T)
{
    __shared__ __align__(16) float Ls[14][16];     // label rows v0-3 .. v0+10
    __shared__ float m1s[VB1][52];                 // mask1 rows (49 used)
    __shared__ __align__(16) float W1s[32][16];
    __shared__ float b1s[32];
    __shared__ float al1s;
    __shared__ int rowOf[VB1][7];
    __shared__ __align__(16) float aggf[VB1 * 784];  // flat f=c*49+ij per vertex (fp32)
    __shared__ __align__(16) uint yts[VB1 * RSTR];   // f1T image (bf16 packed)

    int t = threadIdx.x;
    int v0 = blockIdx.x * VB1;

    for (int e = t; e < 14 * 16; e += NT1) {
        int r = e >> 4, c = e & 15;
        Ls[r][c] = labels[(size_t)(((v0 - 3 + r) + NV) & NMASK) * 16 + c];
    }
    for (int e = t; e < VB1 * 49; e += NT1)
        m1s[e / 49][e % 49] = mask1[(size_t)v0 * 49 + e];
    for (int e = t; e < 512; e += NT1) W1s[e >> 4][e & 15] = W1[e];
    if (t < 32) b1s[t] = b1[t];
    if (t == 0) al1s = al1[0];
    for (int e = t; e < VB1 * 7; e += NT1)
        rowOf[e / 7][e % 7] = (nbrs[v0 * 7 + e] - v0 + 3 + NV) & NMASK;
    __syncthreads();

    // Phase A: agg1 — one (vl,ij) item per thread per round
    for (int it = 0; it < 2; ++it) {
        int w = t + NT1 * it;
        if (w < VB1 * 49) {
            int vl = w / 49, ij = w % 49, i = ij / 7, j = ij % 7;
            float a[16];
            #pragma unroll
            for (int c = 0; c < 16; ++c) a[c] = 0.f;
            #pragma unroll
            for (int u = 0; u < 7; ++u) {
                float mm = m1s[vl][u * 7 + i] * m1s[vl][u * 7 + j];
                const float4* lr = (const float4*)&Ls[rowOf[vl][u]][0];
                float4 l0 = lr[0], l1 = lr[1], l2 = lr[2], l3 = lr[3];
                a[0]+=mm*l0.x; a[1]+=mm*l0.y; a[2]+=mm*l0.z; a[3]+=mm*l0.w;
                a[4]+=mm*l1.x; a[5]+=mm*l1.y; a[6]+=mm*l1.z; a[7]+=mm*l1.w;
                a[8]+=mm*l2.x; a[9]+=mm*l2.y; a[10]+=mm*l2.z; a[11]+=mm*l2.w;
                a[12]+=mm*l3.x; a[13]+=mm*l3.y; a[14]+=mm*l3.z; a[15]+=mm*l3.w;
            }
            float av = al1s * adj1[(size_t)(v0 + vl) * 49 + ij];
            #pragma unroll
            for (int c = 0; c < 16; ++c)
                aggf[vl * 784 + c * 49 + ij] = a[c] + av;
        }
    }
    __syncthreads();

    // Phase B: y = relu(x W1^T + b); x row p = contiguous aggf[p*16..p*16+16)
    for (int it = 0; it < 2; ++it) {
        int w = t + NT1 * it;
        if (w < VB1 * 49) {
            int vl = w / 49, p = w % 49;
            const float4* xp = (const float4*)(aggf + vl * 784 + p * 16);
            float4 x0 = xp[0], x1 = xp[1], x2 = xp[2], x3 = xp[3];
            ushort* yth = (ushort*)yts;
            #pragma unroll
            for (int co = 0; co < 32; ++co) {
                const float4* wr = (const float4*)&W1s[co][0];
                float4 w0 = wr[0], w1 = wr[1], w2 = wr[2], w3 = wr[3];
                float s = b1s[co];
                s += x0.x*w0.x + x0.y*w0.y + x0.z*w0.z + x0.w*w0.w;
                s += x1.x*w1.x + x1.y*w1.y + x1.z*w1.z + x1.w*w1.w;
                s += x2.x*w2.x + x2.y*w2.y + x2.z*w2.z + x2.w*w2.w;
                s += x3.x*w3.x + x3.y*w3.y + x3.z*w3.z + x3.w*w3.w;
                s = fmaxf(s, 0.f);
                int f2 = p * 32 + co, c = f2 / 49, q = f2 % 49;
                yth[(vl * RSTR + q * QSTR + (c >> 1)) * 2 + (c & 1)] = f2bf(s);
            }
        }
    }
    __syncthreads();

    // Phase C: coalesced writeout
    for (int e4 = t; e4 < VB1 * (RSTR / 4); e4 += NT1)
        ((uint4*)(f1T + (size_t)v0 * RSTR))[e4] = ((const uint4*)yts)[e4];
}

// ========== K2F: fused gather + per-vertex MFMA GEMM + channel reduction (no aggB) ==========
#define VBF 8
#define NTF 1024
#define NBF (NV / VBF)   // 512 blocks
__global__ __launch_bounds__(1024) void k2f_kernel(
    const uint* __restrict__ f1T, const int* __restrict__ nbrs,
    const int* __restrict__ idx2, const float* __restrict__ mask2,
    const float* __restrict__ adj2, const float* __restrict__ W2,
    const float* __restrict__ b2, const float* __restrict__ al2,
    float* __restrict__ gpart)
{
    __shared__ __align__(16) uint fs[14 * RSTR];        // 49.7 KB; reused as ybuf after gather
    __shared__ __align__(16) ushort aggT[VBF * 5408];   // 86.5 KB, flat f=c*169+ij per vertex
    __shared__ float m2s[VBF][91];
    __shared__ int   i2s[VBF][91];
    __shared__ int   rowOf[VBF][7];
    __shared__ float al2s;

    int t = threadIdx.x;
    int v0 = blockIdx.x * VBF;

    for (int e = t; e < VBF * 91; e += NTF) {
        m2s[e / 91][e % 91] = mask2[(size_t)v0 * 91 + e];
        i2s[e / 91][e % 91] = idx2[(size_t)v0 * 91 + e];
    }
    for (int e = t; e < VBF * 7; e += NTF)
        rowOf[e / 7][e % 7] = (nbrs[v0 * 7 + e] - v0 + 3 + NV) & NMASK;
    if (t == 0) al2s = al2[0];
    for (int e4 = t; e4 < 14 * (RSTR / 4); e4 += NTF) {
        int r = e4 / (RSTR / 4), w4 = e4 % (RSTR / 4);
        int vv = (v0 - 3 + r + NV) & NMASK;
        ((uint4*)fs)[r * (RSTR / 4) + w4] = ((const uint4*)(f1T + (size_t)vv * RSTR))[w4];
    }
    __syncthreads();

    // ---- gather: agg2 -> aggT (bf16, LDS) ----
    for (int it = 0; it < 2; ++it) {
        int w = t + NTF * it;
        if (w < VBF * KK2) {
            int vl = w / KK2, ij = w % KK2, i = ij / 13, j = ij % 13;
            float acc[32];
            #pragma unroll
            for (int c = 0; c < 32; ++c) acc[c] = 0.f;
            #pragma unroll
            for (int u = 0; u < 7; ++u) {
                float mm = m2s[vl][u * 13 + i] * m2s[vl][u * 13 + j];
                int q = i2s[vl][u * 13 + i] * 7 + i2s[vl][u * 13 + j];
                const uint2* p2 = (const uint2*)(fs + rowOf[vl][u] * RSTR + q * QSTR);
                #pragma unroll
                for (int e = 0; e < 8; ++e) {
                    uint2 d = p2[e];
                    acc[4*e+0] += mm * bflo(d.x);
                    acc[4*e+1] += mm * bfhi(d.x);
                    acc[4*e+2] += mm * bflo(d.y);
                    acc[4*e+3] += mm * bfhi(d.y);
                }
            }
            float av = al2s * adj2[(size_t)(v0 + vl) * KK2 + ij];
            #pragma unroll
            for (int c = 0; c < 32; ++c)
                aggT[vl * 5408 + c * KK2 + ij] = f2bf(acc[c] + av);
        }
    }

    // ---- W2 fragments (B[k][n] = W2[n][k]; same slot->k map as A => exact) ----
    int lane = t & 63, r16 = lane & 15, kg = lane >> 4, wave = t >> 6;
    short8v bf0, bf1;
    #pragma unroll
    for (int e = 0; e < 8; ++e) {
        bf0[e] = (short)f2bf(W2[r16 * 32 + kg * 8 + e]);
        bf1[e] = (short)f2bf(W2[(r16 + 16) * 32 + kg * 8 + e]);
    }
    float bias0 = b2[r16], bias1 = b2[r16 + 16];

    float* ybuf = (float*)fs;       // fs dead after gather
    int ch = t >> 5, s = t & 31;    // 32 threads per g_repr channel
    float gsum = 0.f;

    for (int vl = 0; vl < VBF; ++vl) {
        __syncthreads();            // aggT ready / prev reduce done
        if (wave < 11) {            // 11 p-tiles of 16 rows cover 169
            int p0 = wave * 16;
            int prow = p0 + r16; if (prow > 168) prow = 168;
            const uint4* ap = (const uint4*)((const char*)aggT + vl * 10816 + prow * 64 + kg * 16);
            uint4 araw = *ap;
            short8v a = *reinterpret_cast<short8v*>(&araw);
            float4v z = {0.f, 0.f, 0.f, 0.f};
            float4v d0 = __builtin_amdgcn_mfma_f32_16x16x32_bf16(a, bf0, z, 0, 0, 0);
            float4v d1 = __builtin_amdgcn_mfma_f32_16x16x32_bf16(a, bf1, z, 0, 0, 0);
            #pragma unroll
            for (int r = 0; r < 4; ++r) {
                int p = p0 + kg * 4 + r;
                if (p < KK2) {
                    ybuf[p * 32 + r16]      = fmaxf(d0[r] + bias0, 0.f);
                    ybuf[p * 32 + r16 + 16] = fmaxf(d1[r] + bias1, 0.f);
                }
            }
        }
        __syncthreads();            // ybuf ready
        for (int m = s; m < KK2; m += 32) gsum += ybuf[ch * KK2 + m];
    }
    #pragma unroll
    for (int mask = 16; mask; mask >>= 1) gsum += __shfl_xor(gsum, mask, 32);
    if (s == 0) gpart[blockIdx.x * 32 + ch] = gsum;
}

// ================= final: reduce gpart + FC =================
__global__ __launch_bounds__(256) void fc_kernel(
    const float* __restrict__ gpart, const float* __restrict__ Wfc,
    const float* __restrict__ bfc, float* __restrict__ out)
{
    __shared__ float red[8][32];
    int t = threadIdx.x;
    int ch = t & 31, seg = t >> 5;
    float s = 0.f;
    for (int b = seg; b < NBF; b += 8) s += gpart[b * 32 + ch];
    red[seg][ch] = s;
    __syncthreads();
    if (t < 32) {
        float g = 0.f;
        #pragma unroll
        for (int k = 0; k < 8; ++k) g += red[k][t];
        out[1 + t] = g;
        red[0][t] = g * Wfc[t];
    }
    __syncthreads();
    if (t == 0) {
        float p = bfc[0];
        #pragma unroll
        for (int k = 0; k < 32; ++k) p += red[0][k];
        out[0] = p;
    }
}

// ================= fallback path (round-1 proven, fp32, needs 25.7 MB ws) =================
__global__ __launch_bounds__(64) void lvl1_kernel(
    const float* __restrict__ labels, const int* __restrict__ nbrs,
    const float* __restrict__ mask1, const float* __restrict__ adj1,
    const float* __restrict__ W1, const float* __restrict__ b1,
    const float* __restrict__ al1, float* __restrict__ f1out)
{
    __shared__ float Ls[NN][C0];
    __shared__ float m1s[NN][7];
    __shared__ float a1s[KK1];
    __shared__ float aggsh[C0 * KK1];
    __shared__ float W1s[C1 * 17];
    __shared__ float b1s[C1];
    int v = blockIdx.x, t = threadIdx.x;
    for (int e = t; e < NN * C0; e += 64) {
        int u = e >> 4, c = e & 15;
        Ls[u][c] = labels[(size_t)nbrs[v * NN + u] * C0 + c];
    }
    for (int e = t; e < KK1; e += 64) {
        m1s[e / 7][e % 7] = mask1[(size_t)v * KK1 + e];
        a1s[e] = adj1[(size_t)v * KK1 + e];
    }
    for (int e = t; e < C1 * C0; e += 64) W1s[(e >> 4) * 17 + (e & 15)] = W1[e];
    if (t < C1) b1s[t] = b1[t];
    float alpha = al1[0];
    __syncthreads();
    for (int e = t; e < C0 * KK1; e += 64) {
        int c = e / KK1, ij = e % KK1, i = ij / 7, j = ij % 7;
        float s = 0.f;
        #pragma unroll
        for (int u = 0; u < NN; ++u) s += Ls[u][c] * (m1s[u][i] * m1s[u][j]);
        aggsh[e] = s + alpha * a1s[ij];
    }
    __syncthreads();
    int co = t & 31;
    for (int e = t; e < F1LEN; e += 64) {
        int p = e >> 5;
        float s = b1s[co];
        #pragma unroll
        for (int c = 0; c < C0; ++c) s += aggsh[p * C0 + c] * W1s[co * 17 + c];
        f1out[(size_t)v * F1LEN + e] = fmaxf(s, 0.f);
    }
}

#define F1PAD 56
#define AGPAD 177
__global__ __launch_bounds__(192) void lvl2_kernel(
    const float* __restrict__ f1, const int* __restrict__ nbrs,
    const int* __restrict__ idx2, const float* __restrict__ mask2,
    const float* __restrict__ adj2, const float* __restrict__ W2,
    const float* __restrict__ b2, const float* __restrict__ al2,
    float* __restrict__ gr)
{
    __shared__ float f1s[C1 * F1PAD];
    __shared__ float aggT2[C1 * AGPAD];
    __shared__ float W2s[C2 * C1];
    __shared__ float b2s[C2];
    __shared__ float grs[C2];
    __shared__ int nbs[NN];
    int v = blockIdx.x, t = threadIdx.x;
    if (t < NN) nbs[t] = nbrs[v * NN + t];
    if (t < C2) { b2s[t] = b2[t]; grs[t] = 0.f; }
    for (int e = t; e < C2 * C1; e += 192) W2s[e] = W2[e];
    float alpha = al2[0];
    bool act = (t < KK2);
    float mmr[NN]; int qr[NN];
    float acc[C1];
    if (act) {
        int i = t / 13, j = t % 13;
        const float* mbase = mask2 + (size_t)v * NN * 13;
        const int* ibase = idx2 + (size_t)v * NN * 13;
        #pragma unroll
        for (int u = 0; u < NN; ++u) {
            mmr[u] = mbase[u * 13 + i] * mbase[u * 13 + j];
            qr[u] = ibase[u * 13 + i] * 7 + ibase[u * 13 + j];
        }
    }
    #pragma unroll
    for (int c = 0; c < C1; ++c) acc[c] = 0.f;
    int dst[9]; int nd = 0;
    for (int e = t; e < F1LEN; e += 192) dst[nd++] = (e / 49) * F1PAD + (e % 49);
    for (int u = 0; u < NN; ++u) {
        __syncthreads();
        const float* src = f1 + (size_t)nbs[u] * F1LEN;
        { int k = 0; for (int e = t; e < F1LEN; e += 192) f1s[dst[k++]] = src[e]; }
        __syncthreads();
        if (act) {
            float mv = mmr[u]; int q = qr[u];
            #pragma unroll
            for (int c = 0; c < C1; ++c) acc[c] += mv * f1s[c * F1PAD + q];
        }
    }
    if (act) {
        float a2v = alpha * adj2[(size_t)v * KK2 + t];
        #pragma unroll
        for (int c = 0; c < C1; ++c) {
            int f = c * KK2 + t;
            aggT2[(f & 31) * AGPAD + (f >> 5)] = acc[c] + a2v;
        }
    }
    __syncthreads();
    if (act) {
        int p = t;
        float ar[C1];
        #pragma unroll
        for (int c2 = 0; c2 < C1; ++c2) ar[c2] = aggT2[c2 * AGPAD + p];
        int chA = (p * 32) / KK2;
        int csplit = KK2 - (p * 32 - chA * KK2);
        float sA = 0.f, sB = 0.f;
        #pragma unroll
        for (int co = 0; co < C2; ++co) {
            float s = b2s[co];
            #pragma unroll
            for (int k = 0; k < 8; ++k) {
                float4 wv = *(const float4*)(&W2s[co * C1 + 4 * k]);
                s += ar[4*k+0]*wv.x + ar[4*k+1]*wv.y + ar[4*k+2]*wv.z + ar[4*k+3]*wv.w;
            }
            s = fmaxf(s, 0.f);
            if (co < csplit) sA += s; else sB += s;
        }
        atomicAdd(&grs[chA], sA);
        if (csplit < 32) atomicAdd(&grs[chA + 1], sB);
    }
    __syncthreads();
    if (t < C2) atomicAdd(&gr[t], grs[t]);
}

__global__ __launch_bounds__(64) void fc_small_kernel(
    const float* __restrict__ gr, const float* __restrict__ Wfc,
    const float* __restrict__ bfc, float* __restrict__ out)
{
    int t = threadIdx.x;
    float g = (t < C2) ? gr[t] : 0.f;
    if (t < C2) out[1 + t] = g;
    float p = (t < C2) ? g * Wfc[t] : 0.f;
    #pragma unroll
    for (int off = 32; off > 0; off >>= 1) p += __shfl_down(p, off);
    if (t == 0) out[0] = p + bfc[0];
}

extern "C" void kernel_launch(void* const* d_in, const int* in_sizes, int n_in,
                              void* d_out, int out_size, void* d_ws, size_t ws_size,
                              hipStream_t stream)
{
    const float* labels = (const float*)d_in[0];
    const int*   nbrs   = (const int*)d_in[1];
    /* d_in[2] = idx1: all zeros, unused */
    const float* mask1  = (const float*)d_in[3];
    const int*   idx2   = (const int*)d_in[4];
    const float* mask2  = (const float*)d_in[5];
    const float* adj1   = (const float*)d_in[6];
    const float* adj2   = (const float*)d_in[7];
    const float* W1     = (const float*)d_in[8];
    const float* b1     = (const float*)d_in[9];
    const float* W2     = (const float*)d_in[10];
    const float* b2     = (const float*)d_in[11];
    const float* al1    = (const float*)d_in[12];
    const float* al2    = (const float*)d_in[13];
    const float* Wfc    = (const float*)d_in[14];
    const float* bfc    = (const float*)d_in[15];

    const size_t f1T_bytes = (size_t)NV * RSTR * sizeof(uint);   // 14,548,992
    const size_t need = f1T_bytes + NBF * 32 * sizeof(float) + 128;

    if (ws_size >= need) {
        uint*  f1T   = (uint*)d_ws;
        float* gpart = (float*)((char*)d_ws + f1T_bytes);
        k1_kernel<<<NV / VB1, NT1, 0, stream>>>(labels, nbrs, mask1, adj1, W1, b1, al1, f1T);
        k2f_kernel<<<NBF, NTF, 0, stream>>>(f1T, nbrs, idx2, mask2, adj2, W2, b2, al2, gpart);
        fc_kernel<<<1, 256, 0, stream>>>(gpart, Wfc, bfc, (float*)d_out);
    } else {
        float* f1 = (float*)d_ws;
        float* gr = (float*)((char*)d_ws + (size_t)NV * F1LEN * sizeof(float));
        hipMemsetAsync(gr, 0, C2 * sizeof(float), stream);
        lvl1_kernel<<<NV, 64, 0, stream>>>(labels, nbrs, mask1, adj1, W1, b1, al1, f1);
        lvl2_kernel<<<NV, 192, 0, stream>>>(f1, nbrs, idx2, mask2, adj2, W2, b2, al2, gr);
        fc_small_kernel<<<1, 64, 0, stream>>>(gr, Wfc, bfc, (float*)d_out);
    }
}

// Round 5
// 73.903 us; speedup vs baseline: 3.8219x; 1.0119x over previous
//
#include <hip/hip_runtime.h>

#define NV 4096
#define NMASK 4095
#define NN 7
#define KK1 49
#define KK2 169
#define C0 16
#define C1 32
#define C2 32
#define F1LEN 1568
#define RSTR 888            // u32 words per window row: 49*18=882 used, pad 888
#define QSTR 18
#define VB 8                // vertices per block (fused)
#define NB (NV / VB)        // 512 blocks
#define NT 1024
#define WROWS 14            // f1 window rows = VB+6
#define LROWS 20            // label window rows = VB+12

typedef unsigned int uint;
typedef unsigned short ushort;
typedef __attribute__((ext_vector_type(8))) short short8v;
typedef __attribute__((ext_vector_type(4))) float float4v;

static __device__ __forceinline__ ushort f2bf(float f) {
    union { float f; uint u; } v; v.f = f;
    uint r = (v.u + 0x7fffu + ((v.u >> 16) & 1u)) >> 16;
    return (ushort)r;
}
static __device__ __forceinline__ float bflo(uint w) { return __uint_as_float(w << 16); }
static __device__ __forceinline__ float bfhi(uint w) { return __uint_as_float(w & 0xffff0000u); }

// ================= fused: level-1 (windowed, in-LDS) + gather + level-2 MFMA + fold ==========
__global__ __launch_bounds__(1024) void fused_kernel(
    const float* __restrict__ labels, const int* __restrict__ nbrs,
    const float* __restrict__ mask1, const int* __restrict__ idx2,
    const float* __restrict__ mask2, const float* __restrict__ adj1,
    const float* __restrict__ adj2, const float* __restrict__ W1,
    const float* __restrict__ b1, const float* __restrict__ W2,
    const float* __restrict__ b2, const float* __restrict__ al1,
    const float* __restrict__ al2, float* __restrict__ gpart)
{
    __shared__ __align__(16) uint   fs[WROWS * RSTR];   // 49.7 KB: f1 window (bf16, swizzled)
    __shared__ __align__(16) ushort aggT[VB * 5408];    // 86.5 KB: aggf fp32 (A/B), then agg2 bf16
    __shared__ float m2s[VB][91];
    __shared__ int   i2s[VB][91];
    __shared__ float m1w[WROWS][52];
    __shared__ __align__(16) float Lw[LROWS][16];
    __shared__ int   nbrW[WROWS][NN];
    __shared__ int   rowOf2[VB][NN];
    __shared__ float grs[32];
    __shared__ float al1s, al2s;

    int t = threadIdx.x;
    int v0 = blockIdx.x * VB;
    int lane = t & 63, wvid = t >> 6;        // wave id 0..15
    int r16 = lane & 15, kg = lane >> 4;

    // ---------------- stage ----------------
    if (t < 32) grs[t] = 0.f;
    if (t == 0) { al1s = al1[0]; al2s = al2[0]; }
    for (int e = t; e < LROWS * 16; e += NT) {
        int r = e >> 4, c = e & 15;
        Lw[r][c] = labels[(size_t)(((v0 - 6 + r) + NV) & NMASK) * 16 + c];
    }
    for (int e = t; e < WROWS * 49; e += NT) {
        int r = e / 49, q = e % 49;
        m1w[r][q] = mask1[(size_t)(((v0 - 3 + r) + NV) & NMASK) * 49 + q];
    }
    for (int e = t; e < WROWS * NN; e += NT) {
        int r = e / NN, u = e % NN;
        int wvtx = ((v0 - 3 + r) + NV) & NMASK;
        nbrW[r][u] = (nbrs[wvtx * NN + u] - v0 + 6 + NV) & NMASK;  // label-window row [0,17]
    }
    for (int e = t; e < VB * 91; e += NT) {
        m2s[e / 91][e % 91] = mask2[(size_t)v0 * 91 + e];
        i2s[e / 91][e % 91] = idx2[(size_t)v0 * 91 + e];
    }
    for (int e = t; e < VB * NN; e += NT)
        rowOf2[e / NN][e % NN] = (nbrs[v0 * NN + e] - v0 + 3 + NV) & NMASK;  // [0,13]
    __syncthreads();

    // ---------------- phase A: agg1 for 14 window rows -> aggf (fp32, flat c*49+ij) --------
    float* aggf = (float*)aggT;
    if (t < WROWS * 49) {
        int r = t / 49, ij = t % 49, i = ij / 7, j = ij % 7;
        float a[16];
        #pragma unroll
        for (int c = 0; c < 16; ++c) a[c] = 0.f;
        #pragma unroll
        for (int u = 0; u < NN; ++u) {
            float mm = m1w[r][u * 7 + i] * m1w[r][u * 7 + j];
            const float4* lr = (const float4*)&Lw[nbrW[r][u]][0];
            float4 l0 = lr[0], l1 = lr[1], l2 = lr[2], l3 = lr[3];
            a[0]+=mm*l0.x; a[1]+=mm*l0.y; a[2]+=mm*l0.z; a[3]+=mm*l0.w;
            a[4]+=mm*l1.x; a[5]+=mm*l1.y; a[6]+=mm*l1.z; a[7]+=mm*l1.w;
            a[8]+=mm*l2.x; a[9]+=mm*l2.y; a[10]+=mm*l2.z; a[11]+=mm*l2.w;
            a[12]+=mm*l3.x; a[13]+=mm*l3.y; a[14]+=mm*l3.z; a[15]+=mm*l3.w;
        }
        float av = al1s * adj1[(size_t)(((v0 - 3 + r) + NV) & NMASK) * 49 + ij];
        #pragma unroll
        for (int c = 0; c < 16; ++c)
            aggf[r * 784 + c * 49 + ij] = a[c] + av;
    }
    __syncthreads();

    // ------- phase B: level-1 matmul via zero-padded 16x16x32 MFMA; y -> fs (swizzled) ------
    {
        short8v wb0, wb1;
        #pragma unroll
        for (int e = 0; e < 8; ++e) {
            int k = kg * 8 + e;
            wb0[e] = (k < 16) ? (short)f2bf(W1[r16 * 16 + k]) : (short)0;
            wb1[e] = (k < 16) ? (short)f2bf(W1[(r16 + 16) * 16 + k]) : (short)0;
        }
        float bb0 = b1[r16], bb1 = b1[r16 + 16];
        ushort* fsh = (ushort*)fs;
        for (int tile = wvid; tile < 43; tile += 16) {    // 43 tiles of 16 rows cover 686
            int m = tile * 16 + r16;
            short8v a;
            #pragma unroll
            for (int e = 0; e < 8; ++e) a[e] = 0;
            if (kg < 2 && m < WROWS * 49) {
                int r = m / 49, p = m % 49;
                const float4* xp = (const float4*)(aggf + r * 784 + p * 16 + kg * 8);
                float4 xa = xp[0], xb = xp[1];
                a[0]=(short)f2bf(xa.x); a[1]=(short)f2bf(xa.y); a[2]=(short)f2bf(xa.z); a[3]=(short)f2bf(xa.w);
                a[4]=(short)f2bf(xb.x); a[5]=(short)f2bf(xb.y); a[6]=(short)f2bf(xb.z); a[7]=(short)f2bf(xb.w);
            }
            float4v z = {0.f, 0.f, 0.f, 0.f};
            float4v d0 = __builtin_amdgcn_mfma_f32_16x16x32_bf16(a, wb0, z, 0, 0, 0);
            float4v d1 = __builtin_amdgcn_mfma_f32_16x16x32_bf16(a, wb1, z, 0, 0, 0);
            #pragma unroll
            for (int rr = 0; rr < 4; ++rr) {
                int m2 = tile * 16 + kg * 4 + rr;
                if (m2 < WROWS * 49) {
                    int r = m2 / 49, p = m2 % 49;
                    int f2a = p * 32 + r16;
                    int ca = f2a / 49, qa = f2a % 49;
                    int wa = (ca >> 1) ^ ((qa >> 4) << 1);
                    fsh[(r * RSTR + qa * QSTR + wa) * 2 + (ca & 1)] = f2bf(fmaxf(d0[rr] + bb0, 0.f));
                    int f2b = f2a + 16;
                    int cb = f2b / 49, qb = f2b % 49;
                    int wb = (cb >> 1) ^ ((qb >> 4) << 1);
                    fsh[(r * RSTR + qb * QSTR + wb) * 2 + (cb & 1)] = f2bf(fmaxf(d1[rr] + bb1, 0.f));
                }
            }
        }
    }
    __syncthreads();

    // ---------------- gather: agg2 -> aggT (bf16, flat c*169+ij) ----------------
    #pragma unroll
    for (int it = 0; it < 2; ++it) {
        int w = t + NT * it;
        if (w < VB * KK2) {
            int vl = w / KK2, ij = w % KK2, i = ij / 13, j = ij % 13;
            float acc[32];
            #pragma unroll
            for (int c = 0; c < 32; ++c) acc[c] = 0.f;
            #pragma unroll
            for (int u = 0; u < NN; ++u) {
                float mm = m2s[vl][u * 13 + i] * m2s[vl][u * 13 + j];
                int q = i2s[vl][u * 13 + i] * 7 + i2s[vl][u * 13 + j];
                const uint* base = fs + rowOf2[vl][u] * RSTR + q * QSTR;
                int sw = (q >> 4) << 1;
                #pragma unroll
                for (int e = 0; e < 8; ++e) {
                    uint2 d = *(const uint2*)(base + ((2 * e) ^ sw));
                    acc[4*e+0] += mm * bflo(d.x);
                    acc[4*e+1] += mm * bfhi(d.x);
                    acc[4*e+2] += mm * bflo(d.y);
                    acc[4*e+3] += mm * bfhi(d.y);
                }
            }
            float av = al2s * adj2[(size_t)(v0 + vl) * KK2 + ij];
            #pragma unroll
            for (int c = 0; c < 32; ++c)
                aggT[vl * 5408 + c * KK2 + ij] = f2bf(acc[c] + av);
        }
    }
    __syncthreads();

    // ---------------- level-2 MFMA + register fold (channel loop-invariant) ----------------
    {
        short8v cb0, cb1;
        #pragma unroll
        for (int e = 0; e < 8; ++e) {
            cb0[e] = (short)f2bf(W2[r16 * 32 + kg * 8 + e]);
            cb1[e] = (short)f2bf(W2[(r16 + 16) * 32 + kg * 8 + e]);
        }
        float bias0 = b2[r16], bias1 = b2[r16 + 16];
        if (wvid < 11) {                                  // 11 p-tiles of 16 rows cover 169
            int p0 = wvid * 16;
            int prow = p0 + r16; if (prow > 168) prow = 168;
            float s0[4] = {0.f,0.f,0.f,0.f}, s1[4] = {0.f,0.f,0.f,0.f};
            for (int vl = 0; vl < VB; ++vl) {
                const uint4* ap = (const uint4*)((const char*)aggT + vl * 10816 + prow * 64 + kg * 16);
                uint4 araw = *ap;
                short8v a = *reinterpret_cast<short8v*>(&araw);
                float4v z = {0.f, 0.f, 0.f, 0.f};
                float4v d0 = __builtin_amdgcn_mfma_f32_16x16x32_bf16(a, cb0, z, 0, 0, 0);
                float4v d1 = __builtin_amdgcn_mfma_f32_16x16x32_bf16(a, cb1, z, 0, 0, 0);
                #pragma unroll
                for (int r = 0; r < 4; ++r) {
                    s0[r] += fmaxf(d0[r] + bias0, 0.f);
                    s1[r] += fmaxf(d1[r] + bias1, 0.f);
                }
            }
            #pragma unroll
            for (int r = 0; r < 4; ++r) {
                int p = p0 + kg * 4 + r;
                if (p < KK2) {
                    atomicAdd(&grs[(p * 32 + r16) / KK2], s0[r]);
                    atomicAdd(&grs[(p * 32 + r16 + 16) / KK2], s1[r]);
                }
            }
        }
    }
    __syncthreads();
    if (t < 32) gpart[blockIdx.x * 32 + t] = grs[t];
}

// ================= final: reduce gpart + FC =================
__global__ __launch_bounds__(256) void fc_kernel(
    const float* __restrict__ gpart, const float* __restrict__ Wfc,
    const float* __restrict__ bfc, float* __restrict__ out)
{
    __shared__ float red[8][32];
    int t = threadIdx.x;
    int ch = t & 31, seg = t >> 5;
    float s = 0.f;
    for (int b = seg; b < NB; b += 8) s += gpart[b * 32 + ch];
    red[seg][ch] = s;
    __syncthreads();
    if (t < 32) {
        float g = 0.f;
        #pragma unroll
        for (int k = 0; k < 8; ++k) g += red[k][t];
        out[1 + t] = g;
        red[0][t] = g * Wfc[t];
    }
    __syncthreads();
    if (t == 0) {
        float p = bfc[0];
        #pragma unroll
        for (int k = 0; k < 32; ++k) p += red[0][k];
        out[0] = p;
    }
}

// ================= fallback path (round-1 proven, fp32) =================
__global__ __launch_bounds__(64) void lvl1_kernel(
    const float* __restrict__ labels, const int* __restrict__ nbrs,
    const float* __restrict__ mask1, const float* __restrict__ adj1,
    const float* __restrict__ W1, const float* __restrict__ b1,
    const float* __restrict__ al1, float* __restrict__ f1out)
{
    __shared__ float Ls[NN][C0];
    __shared__ float m1s[NN][7];
    __shared__ float a1s[KK1];
    __shared__ float aggsh[C0 * KK1];
    __shared__ float W1s[C1 * 17];
    __shared__ float b1s[C1];
    int v = blockIdx.x, t = threadIdx.x;
    for (int e = t; e < NN * C0; e += 64) {
        int u = e >> 4, c = e & 15;
        Ls[u][c] = labels[(size_t)nbrs[v * NN + u] * C0 + c];
    }
    for (int e = t; e < KK1; e += 64) {
        m1s[e / 7][e % 7] = mask1[(size_t)v * KK1 + e];
        a1s[e] = adj1[(size_t)v * KK1 + e];
    }
    for (int e = t; e < C1 * C0; e += 64) W1s[(e >> 4) * 17 + (e & 15)] = W1[e];
    if (t < C1) b1s[t] = b1[t];
    float alpha = al1[0];
    __syncthreads();
    for (int e = t; e < C0 * KK1; e += 64) {
        int c = e / KK1, ij = e % KK1, i = ij / 7, j = ij % 7;
        float s = 0.f;
        #pragma unroll
        for (int u = 0; u < NN; ++u) s += Ls[u][c] * (m1s[u][i] * m1s[u][j]);
        aggsh[e] = s + alpha * a1s[ij];
    }
    __syncthreads();
    int co = t & 31;
    for (int e = t; e < F1LEN; e += 64) {
        int p = e >> 5;
        float s = b1s[co];
        #pragma unroll
        for (int c = 0; c < C0; ++c) s += aggsh[p * C0 + c] * W1s[co * 17 + c];
        f1out[(size_t)v * F1LEN + e] = fmaxf(s, 0.f);
    }
}

#define F1PAD 56
#define AGPAD 177
__global__ __launch_bounds__(192) void lvl2_kernel(
    const float* __restrict__ f1, const int* __restrict__ nbrs,
    const int* __restrict__ idx2, const float* __restrict__ mask2,
    const float* __restrict__ adj2, const float* __restrict__ W2,
    const float* __restrict__ b2, const float* __restrict__ al2,
    float* __restrict__ gr)
{
    __shared__ float f1s[C1 * F1PAD];
    __shared__ float aggT2[C1 * AGPAD];
    __shared__ float W2s[C2 * C1];
    __shared__ float b2s[C2];
    __shared__ float grs[C2];
    __shared__ int nbs[NN];
    int v = blockIdx.x, t = threadIdx.x;
    if (t < NN) nbs[t] = nbrs[v * NN + t];
    if (t < C2) { b2s[t] = b2[t]; grs[t] = 0.f; }
    for (int e = t; e < C2 * C1; e += 192) W2s[e] = W2[e];
    float alpha = al2[0];
    bool act = (t < KK2);
    float mmr[NN]; int qr[NN];
    float acc[C1];
    if (act) {
        int i = t / 13, j = t % 13;
        const float* mbase = mask2 + (size_t)v * NN * 13;
        const int* ibase = idx2 + (size_t)v * NN * 13;
        #pragma unroll
        for (int u = 0; u < NN; ++u) {
            mmr[u] = mbase[u * 13 + i] * mbase[u * 13 + j];
            qr[u] = ibase[u * 13 + i] * 7 + ibase[u * 13 + j];
        }
    }
    #pragma unroll
    for (int c = 0; c < C1; ++c) acc[c] = 0.f;
    int dst[9]; int nd = 0;
    for (int e = t; e < F1LEN; e += 192) dst[nd++] = (e / 49) * F1PAD + (e % 49);
    for (int u = 0; u < NN; ++u) {
        __syncthreads();
        const float* src = f1 + (size_t)nbs[u] * F1LEN;
        { int k = 0; for (int e = t; e < F1LEN; e += 192) f1s[dst[k++]] = src[e]; }
        __syncthreads();
        if (act) {
            float mv = mmr[u]; int q = qr[u];
            #pragma unroll
            for (int c = 0; c < C1; ++c) acc[c] += mv * f1s[c * F1PAD + q];
        }
    }
    if (act) {
        float a2v = alpha * adj2[(size_t)v * KK2 + t];
        #pragma unroll
        for (int c = 0; c < C1; ++c) {
            int f = c * KK2 + t;
            aggT2[(f & 31) * AGPAD + (f >> 5)] = acc[c] + a2v;
        }
    }
    __syncthreads();
    if (act) {
        int p = t;
        float ar[C1];
        #pragma unroll
        for (int c2 = 0; c2 < C1; ++c2) ar[c2] = aggT2[c2 * AGPAD + p];
        int chA = (p * 32) / KK2;
        int csplit = KK2 - (p * 32 - chA * KK2);
        float sA = 0.f, sB = 0.f;
        #pragma unroll
        for (int co = 0; co < C2; ++co) {
            float s = b2s[co];
            #pragma unroll
            for (int k = 0; k < 8; ++k) {
                float4 wv = *(const float4*)(&W2s[co * C1 + 4 * k]);
                s += ar[4*k+0]*wv.x + ar[4*k+1]*wv.y + ar[4*k+2]*wv.z + ar[4*k+3]*wv.w;
            }
            s = fmaxf(s, 0.f);
            if (co < csplit) sA += s; else sB += s;
        }
        atomicAdd(&grs[chA], sA);
        if (csplit < 32) atomicAdd(&grs[chA + 1], sB);
    }
    __syncthreads();
    if (t < C2) atomicAdd(&gr[t], grs[t]);
}

__global__ __launch_bounds__(64) void fc_small_kernel(
    const float* __restrict__ gr, const float* __restrict__ Wfc,
    const float* __restrict__ bfc, float* __restrict__ out)
{
    int t = threadIdx.x;
    float g = (t < C2) ? gr[t] : 0.f;
    if (t < C2) out[1 + t] = g;
    float p = (t < C2) ? g * Wfc[t] : 0.f;
    #pragma unroll
    for (int off = 32; off > 0; off >>= 1) p += __shfl_down(p, off);
    if (t == 0) out[0] = p + bfc[0];
}

extern "C" void kernel_launch(void* const* d_in, const int* in_sizes, int n_in,
                              void* d_out, int out_size, void* d_ws, size_t ws_size,
                              hipStream_t stream)
{
    const float* labels = (const float*)d_in[0];
    const int*   nbrs   = (const int*)d_in[1];
    /* d_in[2] = idx1: all zeros, unused */
    const float* mask1  = (const float*)d_in[3];
    const int*   idx2   = (const int*)d_in[4];
    const float* mask2  = (const float*)d_in[5];
    const float* adj1   = (const float*)d_in[6];
    const float* adj2   = (const float*)d_in[7];
    const float* W1     = (const float*)d_in[8];
    const float* b1     = (const float*)d_in[9];
    const float* W2     = (const float*)d_in[10];
    const float* b2     = (const float*)d_in[11];
    const float* al1    = (const float*)d_in[12];
    const float* al2    = (const float*)d_in[13];
    const float* Wfc    = (const float*)d_in[14];
    const float* bfc    = (const float*)d_in[15];

    if (ws_size >= (size_t)NB * 32 * sizeof(float)) {
        float* gpart = (float*)d_ws;       // 64 KB only
        fused_kernel<<<NB, NT, 0, stream>>>(labels, nbrs, mask1, idx2, mask2,
                                            adj1, adj2, W1, b1, W2, b2, al1, al2, gpart);
        fc_kernel<<<1, 256, 0, stream>>>(gpart, Wfc, bfc, (float*)d_out);
    } else {
        float* f1 = (float*)d_ws;
        float* gr = (float*)((char*)d_ws + (size_t)NV * F1LEN * sizeof(float));
        hipMemsetAsync(gr, 0, C2 * sizeof(float), stream);
        lvl1_kernel<<<NV, 64, 0, stream>>>(labels, nbrs, mask1, adj1, W1, b1, al1, f1);
        lvl2_kernel<<<NV, 192, 0, stream>>>(f1, nbrs, idx2, mask2, adj2, W2, b2, al2, gr);
        fc_small_kernel<<<1, 64, 0, stream>>>(gr, Wfc, bfc, (float*)d_out);
    }
}

// Round 6
// 58.024 us; speedup vs baseline: 4.8678x; 1.2737x over previous
//
#include <hip/hip_runtime.h>

#define NV 4096
#define NMASK 4095
#define NN 7
#define KK1 49
#define KK2 169
#define C0 16
#define C1 32
#define C2 32
#define F1LEN 1568
#define RSTR 882            // u32 words per window row: 49*18 exactly
#define QSTR 18
#define VB 4                // vertices per block
#define NB (NV / VB)        // 1024 blocks
#define NT 704              // 11 waves
#define WROWS 10            // f1 window rows = VB+6
#define LROWS 16            // label window rows = VB+12
#define TIL 31              // ceil(WROWS*49 / 16)

typedef unsigned int uint;
typedef unsigned short ushort;
typedef __attribute__((ext_vector_type(8))) short short8v;
typedef __attribute__((ext_vector_type(4))) float float4v;

static __device__ __forceinline__ ushort f2bf(float f) {
    union { float f; uint u; } v; v.f = f;
    uint r = (v.u + 0x7fffu + ((v.u >> 16) & 1u)) >> 16;
    return (ushort)r;
}
static __device__ __forceinline__ float bflo(uint w) { return __uint_as_float(w << 16); }
static __device__ __forceinline__ float bfhi(uint w) { return __uint_as_float(w & 0xffff0000u); }

// ===== fused: level-1 (windowed, in-LDS) + gather + level-2 MFMA + register fold =====
// LDS budget: fs 35,280 + aggT 43,264 + rowOf2 112 + grs 128 + al 8 = 78,792 B -> 2 blocks/CU
__global__ __launch_bounds__(704) void fused_kernel(
    const float* __restrict__ labels, const int* __restrict__ nbrs,
    const float* __restrict__ mask1, const int* __restrict__ idx2,
    const float* __restrict__ mask2, const float* __restrict__ adj1,
    const float* __restrict__ adj2, const float* __restrict__ W1,
    const float* __restrict__ b1, const float* __restrict__ W2,
    const float* __restrict__ b2, const float* __restrict__ al1,
    const float* __restrict__ al2, float* __restrict__ gpart)
{
    __shared__ __align__(16) uint   fs[WROWS * RSTR];   // f1 window (bf16 packed, swizzled)
    __shared__ __align__(16) ushort aggT[VB * 5408];    // phase A/B: aggf+m1w+Lw+nbrW; then agg2 bf16
    __shared__ int   rowOf2[VB][NN];
    __shared__ float grs[32];
    __shared__ float al1s, al2s;

    // aliases into aggT (dead once gather starts writing agg2)
    float* aggf = (float*)aggT;                    // [WROWS*784] fp32 = 31,360 B
    float* Lw   = (float*)((char*)aggT + 31360);   // [LROWS*16]  = 1,024 B (16B aligned)
    float* m1w  = (float*)((char*)aggT + 32384);   // [WROWS*49]  = 1,960 B
    int*   nbrW = (int*)  ((char*)aggT + 34344);   // [WROWS*7]   = 280 B

    int t = threadIdx.x;
    int v0 = blockIdx.x * VB;
    int lane = t & 63, wvid = t >> 6;              // 11 waves
    int r16 = lane & 15, kg = lane >> 4;

    // ---------------- stage ----------------
    if (t < 32) grs[t] = 0.f;
    if (t == 0) { al1s = al1[0]; al2s = al2[0]; }
    for (int e = t; e < LROWS * 16; e += NT)
        Lw[e] = labels[(size_t)(((v0 - 6 + (e >> 4)) + NV) & NMASK) * 16 + (e & 15)];
    for (int e = t; e < WROWS * 49; e += NT)
        m1w[e] = mask1[(size_t)(((v0 - 3 + e / 49) + NV) & NMASK) * 49 + (e % 49)];
    for (int e = t; e < WROWS * NN; e += NT) {
        int r = e / NN, u = e % NN;
        nbrW[e] = (nbrs[(size_t)(((v0 - 3 + r) + NV) & NMASK) * NN + u] - v0 + 6 + NV) & NMASK;
    }
    for (int e = t; e < VB * NN; e += NT)
        rowOf2[e / NN][e % NN] = (nbrs[v0 * NN + e] - v0 + 3 + NV) & NMASK;
    __syncthreads();

    // ---------------- phase A: agg1 for 10 window rows -> aggf (fp32, flat c*49+ij) -------
    if (t < WROWS * 49) {
        int r = t / 49, ij = t % 49, i = ij / 7, j = ij % 7;
        float a[16];
        #pragma unroll
        for (int c = 0; c < 16; ++c) a[c] = 0.f;
        #pragma unroll
        for (int u = 0; u < NN; ++u) {
            float mm = m1w[r * 49 + u * 7 + i] * m1w[r * 49 + u * 7 + j];
            const float4* lr = (const float4*)&Lw[nbrW[r * 7 + u] * 16];
            float4 l0 = lr[0], l1 = lr[1], l2 = lr[2], l3 = lr[3];
            a[0]+=mm*l0.x; a[1]+=mm*l0.y; a[2]+=mm*l0.z; a[3]+=mm*l0.w;
            a[4]+=mm*l1.x; a[5]+=mm*l1.y; a[6]+=mm*l1.z; a[7]+=mm*l1.w;
            a[8]+=mm*l2.x; a[9]+=mm*l2.y; a[10]+=mm*l2.z; a[11]+=mm*l2.w;
            a[12]+=mm*l3.x; a[13]+=mm*l3.y; a[14]+=mm*l3.z; a[15]+=mm*l3.w;
        }
        float av = al1s * adj1[(size_t)(((v0 - 3 + r) + NV) & NMASK) * 49 + ij];
        #pragma unroll
        for (int c = 0; c < 16; ++c)
            aggf[r * 784 + c * 49 + ij] = a[c] + av;
    }
    __syncthreads();

    // ------- phase B: level-1 matmul via zero-padded 16x16x32 MFMA; y -> fs (swizzled) -----
    {
        short8v wb0, wb1;
        #pragma unroll
        for (int e = 0; e < 8; ++e) {
            int k = kg * 8 + e;
            wb0[e] = (k < 16) ? (short)f2bf(W1[r16 * 16 + k]) : (short)0;
            wb1[e] = (k < 16) ? (short)f2bf(W1[(r16 + 16) * 16 + k]) : (short)0;
        }
        float bb0 = b1[r16], bb1 = b1[r16 + 16];
        ushort* fsh = (ushort*)fs;
        for (int tile = wvid; tile < TIL; tile += 11) {
            int m = tile * 16 + r16;
            short8v a;
            #pragma unroll
            for (int e = 0; e < 8; ++e) a[e] = 0;
            if (kg < 2 && m < WROWS * 49) {
                int r = m / 49, p = m % 49;
                const float4* xp = (const float4*)(aggf + r * 784 + p * 16 + kg * 8);
                float4 xa = xp[0], xb = xp[1];
                a[0]=(short)f2bf(xa.x); a[1]=(short)f2bf(xa.y); a[2]=(short)f2bf(xa.z); a[3]=(short)f2bf(xa.w);
                a[4]=(short)f2bf(xb.x); a[5]=(short)f2bf(xb.y); a[6]=(short)f2bf(xb.z); a[7]=(short)f2bf(xb.w);
            }
            float4v z = {0.f, 0.f, 0.f, 0.f};
            float4v d0 = __builtin_amdgcn_mfma_f32_16x16x32_bf16(a, wb0, z, 0, 0, 0);
            float4v d1 = __builtin_amdgcn_mfma_f32_16x16x32_bf16(a, wb1, z, 0, 0, 0);
            #pragma unroll
            for (int rr = 0; rr < 4; ++rr) {
                int m2 = tile * 16 + kg * 4 + rr;
                if (m2 < WROWS * 49) {
                    int r = m2 / 49, p = m2 % 49;
                    int f2a = p * 32 + r16;
                    int ca = f2a / 49, qa = f2a % 49;
                    int wa = (ca >> 1) ^ ((qa >> 4) << 1);
                    fsh[(r * RSTR + qa * QSTR + wa) * 2 + (ca & 1)] = f2bf(fmaxf(d0[rr] + bb0, 0.f));
                    int f2b = f2a + 16;
                    int cb = f2b / 49, qb = f2b % 49;
                    int wb = (cb >> 1) ^ ((qb >> 4) << 1);
                    fsh[(r * RSTR + qb * QSTR + wb) * 2 + (cb & 1)] = f2bf(fmaxf(d1[rr] + bb1, 0.f));
                }
            }
        }
    }
    __syncthreads();

    // ---------------- gather: agg2 -> aggT (bf16, flat c*169+ij); one round ----------------
    if (t < VB * KK2) {
        int vl = t / KK2, ij = t % KK2, i = ij / 13, j = ij % 13;
        int v = v0 + vl;
        const float* mb = mask2 + (size_t)v * 91;
        const int*   ib = idx2 + (size_t)v * 91;
        float acc[32];
        #pragma unroll
        for (int c = 0; c < 32; ++c) acc[c] = 0.f;
        #pragma unroll
        for (int u = 0; u < NN; ++u) {
            float mm = mb[u * 13 + i] * mb[u * 13 + j];
            int q = ib[u * 13 + i] * 7 + ib[u * 13 + j];
            const uint* base = fs + rowOf2[vl][u] * RSTR + q * QSTR;
            int sw = (q >> 4) << 1;
            #pragma unroll
            for (int e = 0; e < 8; ++e) {
                uint2 d = *(const uint2*)(base + ((2 * e) ^ sw));
                acc[4*e+0] += mm * bflo(d.x);
                acc[4*e+1] += mm * bfhi(d.x);
                acc[4*e+2] += mm * bflo(d.y);
                acc[4*e+3] += mm * bfhi(d.y);
            }
        }
        float av = al2s * adj2[(size_t)v * KK2 + ij];
        #pragma unroll
        for (int c = 0; c < 32; ++c)
            aggT[vl * 5408 + c * KK2 + ij] = f2bf(acc[c] + av);
    }
    __syncthreads();

    // ------- level-2 MFMA + in-register channel fold (<=4 channels per wave) + butterfly ----
    {
        short8v cb0, cb1;
        #pragma unroll
        for (int e = 0; e < 8; ++e) {
            cb0[e] = (short)f2bf(W2[r16 * 32 + kg * 8 + e]);
            cb1[e] = (short)f2bf(W2[(r16 + 16) * 32 + kg * 8 + e]);
        }
        float bias0 = b2[r16], bias1 = b2[r16 + 16];
        int p0 = wvid * 16;                       // wave <-> p-tile, 11 waves = 11 tiles
        int prow = p0 + r16; if (prow > 168) prow = 168;
        float s0[4] = {0.f,0.f,0.f,0.f}, s1[4] = {0.f,0.f,0.f,0.f};
        #pragma unroll
        for (int vl = 0; vl < VB; ++vl) {
            const uint4* ap = (const uint4*)((const char*)aggT + vl * 10816 + prow * 64 + kg * 16);
            uint4 araw = *ap;
            short8v a = *reinterpret_cast<short8v*>(&araw);
            float4v z = {0.f, 0.f, 0.f, 0.f};
            float4v d0 = __builtin_amdgcn_mfma_f32_16x16x32_bf16(a, cb0, z, 0, 0, 0);
            float4v d1 = __builtin_amdgcn_mfma_f32_16x16x32_bf16(a, cb1, z, 0, 0, 0);
            #pragma unroll
            for (int r = 0; r < 4; ++r) {
                s0[r] += fmaxf(d0[r] + bias0, 0.f);
                s1[r] += fmaxf(d1[r] + bias1, 0.f);
            }
        }
        int chA = (p0 * 32) / KK2;                // wave-uniform base channel
        float part0 = 0.f, part1 = 0.f, part2 = 0.f, part3 = 0.f;
        #pragma unroll
        for (int r = 0; r < 4; ++r) {
            int p = p0 + kg * 4 + r;
            if (p < KK2) {
                int c0 = (p * 32 + r16) / KK2 - chA;
                part0 += (c0 == 0) ? s0[r] : 0.f;
                part1 += (c0 == 1) ? s0[r] : 0.f;
                part2 += (c0 == 2) ? s0[r] : 0.f;
                part3 += (c0 == 3) ? s0[r] : 0.f;
                int c1 = (p * 32 + r16 + 16) / KK2 - chA;
                part0 += (c1 == 0) ? s1[r] : 0.f;
                part1 += (c1 == 1) ? s1[r] : 0.f;
                part2 += (c1 == 2) ? s1[r] : 0.f;
                part3 += (c1 == 3) ? s1[r] : 0.f;
            }
        }
        #pragma unroll
        for (int off = 32; off > 0; off >>= 1) {
            part0 += __shfl_xor(part0, off);
            part1 += __shfl_xor(part1, off);
            part2 += __shfl_xor(part2, off);
            part3 += __shfl_xor(part3, off);
        }
        if (lane == 0) {
            atomicAdd(&grs[chA], part0);
            if (chA + 1 < 32) atomicAdd(&grs[chA + 1], part1);
            if (chA + 2 < 32) atomicAdd(&grs[chA + 2], part2);
            if (chA + 3 < 32) atomicAdd(&grs[chA + 3], part3);
        }
    }
    __syncthreads();
    if (t < 32) gpart[blockIdx.x * 32 + t] = grs[t];
}

// ================= final: reduce gpart + FC =================
__global__ __launch_bounds__(1024) void fc_kernel(
    const float* __restrict__ gpart, const float* __restrict__ Wfc,
    const float* __restrict__ bfc, float* __restrict__ out)
{
    __shared__ float red[32][33];
    int t = threadIdx.x;
    int ch = t & 31, seg = t >> 5;
    float s = 0.f;
    for (int b = seg; b < NB; b += 32) s += gpart[b * 32 + ch];
    red[seg][ch] = s;
    __syncthreads();
    if (t < 32) {
        float g = 0.f;
        #pragma unroll
        for (int k = 0; k < 32; ++k) g += red[k][t];
        out[1 + t] = g;
        red[0][t] = g * Wfc[t];
    }
    __syncthreads();
    if (t == 0) {
        float p = bfc[0];
        #pragma unroll
        for (int k = 0; k < 32; ++k) p += red[0][k];
        out[0] = p;
    }
}

// ================= fallback path (round-1 proven, fp32) =================
__global__ __launch_bounds__(64) void lvl1_kernel(
    const float* __restrict__ labels, const int* __restrict__ nbrs,
    const float* __restrict__ mask1, const float* __restrict__ adj1,
    const float* __restrict__ W1, const float* __restrict__ b1,
    const float* __restrict__ al1, float* __restrict__ f1out)
{
    __shared__ float Ls[NN][C0];
    __shared__ float m1s[NN][7];
    __shared__ float a1s[KK1];
    __shared__ float aggsh[C0 * KK1];
    __shared__ float W1s[C1 * 17];
    __shared__ float b1s[C1];
    int v = blockIdx.x, t = threadIdx.x;
    for (int e = t; e < NN * C0; e += 64) {
        int u = e >> 4, c = e & 15;
        Ls[u][c] = labels[(size_t)nbrs[v * NN + u] * C0 + c];
    }
    for (int e = t; e < KK1; e += 64) {
        m1s[e / 7][e % 7] = mask1[(size_t)v * KK1 + e];
        a1s[e] = adj1[(size_t)v * KK1 + e];
    }
    for (int e = t; e < C1 * C0; e += 64) W1s[(e >> 4) * 17 + (e & 15)] = W1[e];
    if (t < C1) b1s[t] = b1[t];
    float alpha = al1[0];
    __syncthreads();
    for (int e = t; e < C0 * KK1; e += 64) {
        int c = e / KK1, ij = e % KK1, i = ij / 7, j = ij % 7;
        float s = 0.f;
        #pragma unroll
        for (int u = 0; u < NN; ++u) s += Ls[u][c] * (m1s[u][i] * m1s[u][j]);
        aggsh[e] = s + alpha * a1s[ij];
    }
    __syncthreads();
    int co = t & 31;
    for (int e = t; e < F1LEN; e += 64) {
        int p = e >> 5;
        float s = b1s[co];
        #pragma unroll
        for (int c = 0; c < C0; ++c) s += aggsh[p * C0 + c] * W1s[co * 17 + c];
        f1out[(size_t)v * F1LEN + e] = fmaxf(s, 0.f);
    }
}

#define F1PAD 56
#define AGPAD 177
__global__ __launch_bounds__(192) void lvl2_kernel(
    const float* __restrict__ f1, const int* __restrict__ nbrs,
    const int* __restrict__ idx2, const float* __restrict__ mask2,
    const float* __restrict__ adj2, const float* __restrict__ W2,
    const float* __restrict__ b2, const float* __restrict__ al2,
    float* __restrict__ gr)
{
    __shared__ float f1s[C1 * F1PAD];
    __shared__ float aggT2[C1 * AGPAD];
    __shared__ float W2s[C2 * C1];
    __shared__ float b2s[C2];
    __shared__ float grs[C2];
    __shared__ int nbs[NN];
    int v = blockIdx.x, t = threadIdx.x;
    if (t < NN) nbs[t] = nbrs[v * NN + t];
    if (t < C2) { b2s[t] = b2[t]; grs[t] = 0.f; }
    for (int e = t; e < C2 * C1; e += 192) W2s[e] = W2[e];
    float alpha = al2[0];
    bool act = (t < KK2);
    float mmr[NN]; int qr[NN];
    float acc[C1];
    if (act) {
        int i = t / 13, j = t % 13;
        const float* mbase = mask2 + (size_t)v * NN * 13;
        const int* ibase = idx2 + (size_t)v * NN * 13;
        #pragma unroll
        for (int u = 0; u < NN; ++u) {
            mmr[u] = mbase[u * 13 + i] * mbase[u * 13 + j];
            qr[u] = ibase[u * 13 + i] * 7 + ibase[u * 13 + j];
        }
    }
    #pragma unroll
    for (int c = 0; c < C1; ++c) acc[c] = 0.f;
    int dst[9]; int nd = 0;
    for (int e = t; e < F1LEN; e += 192) dst[nd++] = (e / 49) * F1PAD + (e % 49);
    for (int u = 0; u < NN; ++u) {
        __syncthreads();
        const float* src = f1 + (size_t)nbs[u] * F1LEN;
        { int k = 0; for (int e = t; e < F1LEN; e += 192) f1s[dst[k++]] = src[e]; }
        __syncthreads();
        if (act) {
            float mv = mmr[u]; int q = qr[u];
            #pragma unroll
            for (int c = 0; c < C1; ++c) acc[c] += mv * f1s[c * F1PAD + q];
        }
    }
    if (act) {
        float a2v = alpha * adj2[(size_t)v * KK2 + t];
        #pragma unroll
        for (int c = 0; c < C1; ++c) {
            int f = c * KK2 + t;
            aggT2[(f & 31) * AGPAD + (f >> 5)] = acc[c] + a2v;
        }
    }
    __syncthreads();
    if (act) {
        int p = t;
        float ar[C1];
        #pragma unroll
        for (int c2 = 0; c2 < C1; ++c2) ar[c2] = aggT2[c2 * AGPAD + p];
        int chA = (p * 32) / KK2;
        int csplit = KK2 - (p * 32 - chA * KK2);
        float sA = 0.f, sB = 0.f;
        #pragma unroll
        for (int co = 0; co < C2; ++co) {
            float s = b2s[co];
            #pragma unroll
            for (int k = 0; k < 8; ++k) {
                float4 wv = *(const float4*)(&W2s[co * C1 + 4 * k]);
                s += ar[4*k+0]*wv.x + ar[4*k+1]*wv.y + ar[4*k+2]*wv.z + ar[4*k+3]*wv.w;
            }
            s = fmaxf(s, 0.f);
            if (co < csplit) sA += s; else sB += s;
        }
        atomicAdd(&grs[chA], sA);
        if (csplit < 32) atomicAdd(&grs[chA + 1], sB);
    }
    __syncthreads();
    if (t < C2) atomicAdd(&gr[t], grs[t]);
}

__global__ __launch_bounds__(64) void fc_small_kernel(
    const float* __restrict__ gr, const float* __restrict__ Wfc,
    const float* __restrict__ bfc, float* __restrict__ out)
{
    int t = threadIdx.x;
    float g = (t < C2) ? gr[t] : 0.f;
    if (t < C2) out[1 + t] = g;
    float p = (t < C2) ? g * Wfc[t] : 0.f;
    #pragma unroll
    for (int off = 32; off > 0; off >>= 1) p += __shfl_down(p, off);
    if (t == 0) out[0] = p + bfc[0];
}

extern "C" void kernel_launch(void* const* d_in, const int* in_sizes, int n_in,
                              void* d_out, int out_size, void* d_ws, size_t ws_size,
                              hipStream_t stream)
{
    const float* labels = (const float*)d_in[0];
    const int*   nbrs   = (const int*)d_in[1];
    /* d_in[2] = idx1: all zeros, unused */
    const float* mask1  = (const float*)d_in[3];
    const int*   idx2   = (const int*)d_in[4];
    const float* mask2  = (const float*)d_in[5];
    const float* adj1   = (const float*)d_in[6];
    const float* adj2   = (const float*)d_in[7];
    const float* W1     = (const float*)d_in[8];
    const float* b1     = (const float*)d_in[9];
    const float* W2     = (const float*)d_in[10];
    const float* b2     = (const float*)d_in[11];
    const float* al1    = (const float*)d_in[12];
    const float* al2    = (const float*)d_in[13];
    const float* Wfc    = (const float*)d_in[14];
    const float* bfc    = (const float*)d_in[15];

    if (ws_size >= (size_t)NB * 32 * sizeof(float) + 128) {
        float* gpart = (float*)d_ws;       // 128 KB
        fused_kernel<<<NB, NT, 0, stream>>>(labels, nbrs, mask1, idx2, mask2,
                                            adj1, adj2, W1, b1, W2, b2, al1, al2, gpart);
        fc_kernel<<<1, 1024, 0, stream>>>(gpart, Wfc, bfc, (float*)d_out);
    } else {
        float* f1 = (float*)d_ws;
        float* gr = (float*)((char*)d_ws + (size_t)NV * F1LEN * sizeof(float));
        hipMemsetAsync(gr, 0, C2 * sizeof(float), stream);
        lvl1_kernel<<<NV, 64, 0, stream>>>(labels, nbrs, mask1, adj1, W1, b1, al1, f1);
        lvl2_kernel<<<NV, 192, 0, stream>>>(f1, nbrs, idx2, mask2, adj2, W2, b2, al2, gr);
        fc_small_kernel<<<1, 64, 0, stream>>>(gr, Wfc, bfc, (float*)d_out);
    }
}